// Round 1
// baseline (2858.454 us; speedup 1.0000x reference)
//
#include <hip/hip_runtime.h>
#include <math.h>

#define T 1024
#define H 1024
#define NH 8
#define NKV 4
#define HD 128
#define NE 32
#define TOPK 4
#define NG 8
#define MI 512
#define SI 1024
#define RSF 2.5f
#define EPS 1e-6f

#define GT 64
#define GKT 16
#define LDP 68

// ---------------- elementwise / norm ----------------
__global__ void rmsnorm_kernel(const float* __restrict__ x, const float* __restrict__ w,
                               float* __restrict__ out) {
    int t = blockIdx.x;
    __shared__ float red[256];
    const float* xr = x + (size_t)t * H;
    float s = 0.f;
    for (int i = threadIdx.x; i < H; i += 256) { float v = xr[i]; s += v * v; }
    red[threadIdx.x] = s;
    __syncthreads();
    for (int st = 128; st > 0; st >>= 1) {
        if (threadIdx.x < st) red[threadIdx.x] += red[threadIdx.x + st];
        __syncthreads();
    }
    float inv = rsqrtf(red[0] / (float)H + EPS);
    float* orow = out + (size_t)t * H;
    for (int i = threadIdx.x; i < H; i += 256) orow[i] = xr[i] * inv * w[i];
}

__global__ void add2_kernel(const float* __restrict__ a, const float* __restrict__ b,
                            float* __restrict__ o, int n) {
    int i = blockIdx.x * 256 + threadIdx.x;
    if (i < n) o[i] = a[i] + b[i];
}

__global__ void add3_kernel(const float* __restrict__ a, const float* __restrict__ b,
                            const float* __restrict__ c, float* __restrict__ o, int n) {
    int i = blockIdx.x * 256 + threadIdx.x;
    if (i < n) o[i] = a[i] + b[i] + c[i];
}

__global__ void zero_i_kernel(int* p, int n) {
    int i = blockIdx.x * 256 + threadIdx.x;
    if (i < n) p[i] = 0;
}
__global__ void zero_f_kernel(float* p, int n) {
    int i = blockIdx.x * 256 + threadIdx.x;
    if (i < n) p[i] = 0.f;
}

// ---------------- generic tiled SGEMM ----------------
// C[M,N] = A[M,K] * op(B).  BT=true: B is (N,K) row-major (C=A@B^T).
//                           BT=false: B is (K,N) row-major (C=A@B).
template <bool BT>
__global__ void gemm_kernel(const float* __restrict__ A, const float* __restrict__ B,
                            float* __restrict__ C, int M, int N, int K) {
    __shared__ float As[GKT][LDP];
    __shared__ float Bs[GKT][LDP];
    int tid = threadIdx.x;
    int tx = tid & 15, ty = tid >> 4;
    int m0 = blockIdx.y * GT, n0 = blockIdx.x * GT;
    float acc[4][4] = {};
    for (int k0 = 0; k0 < K; k0 += GKT) {
        for (int mm = ty; mm < GT; mm += 16) {
            int gm = m0 + mm;
            As[tx][mm] = (gm < M) ? A[(size_t)gm * K + k0 + tx] : 0.f;
        }
        if (BT) {
            for (int nn = ty; nn < GT; nn += 16) {
                int gn = n0 + nn;
                Bs[tx][nn] = (gn < N) ? B[(size_t)gn * K + k0 + tx] : 0.f;
            }
        } else {
            int nL = tid & 63;
            int gn = n0 + nL;
            for (int kk = tid >> 6; kk < GKT; kk += 4)
                Bs[kk][nL] = (gn < N) ? B[(size_t)(k0 + kk) * N + gn] : 0.f;
        }
        __syncthreads();
#pragma unroll
        for (int kk = 0; kk < GKT; ++kk) {
            float4 a4 = *(const float4*)&As[kk][ty * 4];
            float4 b4 = *(const float4*)&Bs[kk][tx * 4];
            float av[4] = {a4.x, a4.y, a4.z, a4.w};
            float bv[4] = {b4.x, b4.y, b4.z, b4.w};
#pragma unroll
            for (int i = 0; i < 4; ++i)
#pragma unroll
                for (int j = 0; j < 4; ++j) acc[i][j] += av[i] * bv[j];
        }
        __syncthreads();
    }
    for (int i = 0; i < 4; ++i) {
        int gm = m0 + ty * 4 + i;
        if (gm >= M) continue;
        for (int j = 0; j < 4; ++j) {
            int gn = n0 + tx * 4 + j;
            if (gn < N) C[(size_t)gm * N + gn] = acc[i][j];
        }
    }
}

// ---------------- rope ----------------
__global__ void rope_kernel(float* __restrict__ q, float* __restrict__ k,
                            const int* __restrict__ pos) {
    int i = blockIdx.x * 256 + threadIdx.x;
    const int totq = T * NH * 64;
    const int tot = totq + T * NKV * 64;
    if (i >= tot) return;
    float* buf;
    int t, hh, d, nh;
    if (i < totq) {
        buf = q; nh = NH;
        int r = i; d = r & 63; r >>= 6; hh = r % NH; t = r / NH;
    } else {
        buf = k; nh = NKV;
        int r = i - totq; d = r & 63; r >>= 6; hh = r % NKV; t = r / NKV;
    }
    float p = (float)pos[t];
    float inv = powf(10000.0f, -(float)d / 64.0f);
    float fr = p * inv;
    float sv, cv;
    sincosf(fr, &sv, &cv);
    size_t bi = ((size_t)t * nh + hh) * HD + d;
    float x1 = buf[bi], x2 = buf[bi + 64];
    buf[bi] = x1 * cv - x2 * sv;
    buf[bi + 64] = x2 * cv + x1 * sv;
}

// ---------------- flash attention (causal, GQA) ----------------
__global__ void attn_kernel(const float* __restrict__ Q, const float* __restrict__ Kb,
                            const float* __restrict__ Vb, float* __restrict__ O) {
    int h = blockIdx.x;
    int qb = blockIdx.y;
    int kvh = h >> 1;  // rep = NH/NKV = 2
    __shared__ float Qs[32][HD + 1];
    __shared__ float Ks[32][HD + 1];
    __shared__ float Vs[32][HD + 1];
    __shared__ float Ss[32][33];
    __shared__ float mrow[32], lrow[32], arow[32];
    int tid = threadIdx.x;
    int q0 = qb * 32;
    for (int i = tid; i < 32 * HD; i += 256) {
        int r = i >> 7, d = i & 127;
        Qs[r][d] = Q[((size_t)(q0 + r) * NH + h) * HD + d];
    }
    if (tid < 32) { mrow[tid] = -INFINITY; lrow[tid] = 0.f; }
    __syncthreads();
    int row = tid >> 3, seg = tid & 7;
    float oacc[16];
#pragma unroll
    for (int d = 0; d < 16; ++d) oacc[d] = 0.f;
    const float scale = 0.08838834764831845f;  // 1/sqrt(128)
    for (int k0 = 0; k0 <= q0; k0 += 32) {
        for (int i = tid; i < 32 * HD; i += 256) {
            int r = i >> 7, d = i & 127;
            Ks[r][d] = Kb[((size_t)(k0 + r) * NKV + kvh) * HD + d];
            Vs[r][d] = Vb[((size_t)(k0 + r) * NKV + kvh) * HD + d];
        }
        __syncthreads();
#pragma unroll
        for (int j = 0; j < 4; ++j) {
            int col = seg * 4 + j;
            float s = 0.f;
            for (int d = 0; d < HD; ++d) s += Qs[row][d] * Ks[col][d];
            s *= scale;
            if (k0 + col > q0 + row) s = -INFINITY;
            Ss[row][col] = s;
        }
        __syncthreads();
        if (tid < 32) {
            int r = tid;
            float m = mrow[r], mn = m;
            for (int c = 0; c < 32; ++c) mn = fmaxf(mn, Ss[r][c]);
            float alpha = __expf(m - mn);
            float l = lrow[r] * alpha;
            for (int c = 0; c < 32; ++c) {
                float p = __expf(Ss[r][c] - mn);
                Ss[r][c] = p;
                l += p;
            }
            mrow[r] = mn; lrow[r] = l; arow[r] = alpha;
        }
        __syncthreads();
        float alpha = arow[row];
#pragma unroll
        for (int d = 0; d < 16; ++d) {
            int dd = seg * 16 + d;
            float acc2 = oacc[d] * alpha;
            for (int c = 0; c < 32; ++c) acc2 += Ss[row][c] * Vs[c][dd];
            oacc[d] = acc2;
        }
        __syncthreads();
    }
    float linv = 1.f / lrow[row];
    for (int d = 0; d < 16; ++d)
        O[((size_t)(q0 + row) * NH + h) * HD + seg * 16 + d] = oacc[d] * linv;
}

// ---------------- router ----------------
__global__ void router_kernel(const float* __restrict__ logits, const float* __restrict__ bias,
                              int* __restrict__ topk_idx, float* __restrict__ topkw) {
    int t = blockIdx.x * 256 + threadIdx.x;
    if (t >= T) return;
    float sc[NE], sfc[NE];
    for (int e = 0; e < NE; ++e) {
        float s = 1.f / (1.f + expf(-logits[(size_t)t * NE + e]));
        sc[e] = s;
        sfc[e] = s + bias[e];
    }
    // group score = sum of top-2 within each group of 4
    float gs[NG];
    for (int g = 0; g < NG; ++g) {
        float m1 = -1e30f, m2 = -1e30f;
        for (int i = 0; i < 4; ++i) {
            float v = sfc[g * 4 + i];
            if (v > m1) { m2 = m1; m1 = v; }
            else if (v > m2) m2 = v;
        }
        gs[g] = m1 + m2;
    }
    // top-4 groups (strict > keeps lowest index on ties, matching lax.top_k)
    bool gmask[NG];
    for (int g = 0; g < NG; ++g) gmask[g] = false;
    for (int r = 0; r < 4; ++r) {
        int bi = 0; float bv = -1e30f;
        for (int g = 0; g < NG; ++g)
            if (gs[g] > bv) { bv = gs[g]; bi = g; }
        gmask[bi] = true;
        gs[bi] = -1e30f;
    }
    float msfc[NE];
    for (int e = 0; e < NE; ++e) msfc[e] = gmask[e >> 2] ? sfc[e] : 0.f;
    // top-4 experts
    int idx[TOPK]; float w[TOPK]; float wsum = 0.f;
    for (int r = 0; r < TOPK; ++r) {
        int bi = 0; float bv = -1e30f;
        for (int e = 0; e < NE; ++e)
            if (msfc[e] > bv) { bv = msfc[e]; bi = e; }
        idx[r] = bi;
        msfc[bi] = -1e30f;
        w[r] = sc[bi];
        wsum += w[r];
    }
    float inv = RSF / (wsum + 1e-20f);
    for (int r = 0; r < TOPK; ++r) {
        topk_idx[(size_t)t * TOPK + r] = idx[r];
        topkw[(size_t)t * TOPK + r] = w[r] * inv;
    }
}

__global__ void count_kernel(const int* __restrict__ topk_idx, int* __restrict__ counts) {
    int i = blockIdx.x * 256 + threadIdx.x;
    if (i < T * TOPK) atomicAdd(&counts[topk_idx[i]], 1);
}
__global__ void scan_kernel(const int* __restrict__ counts, int* __restrict__ offs) {
    if (threadIdx.x == 0 && blockIdx.x == 0) {
        int acc = 0;
        for (int e = 0; e < NE; ++e) { offs[e] = acc; acc += counts[e]; }
    }
}
__global__ void fill_kernel(const int* __restrict__ topk_idx, const float* __restrict__ topkw,
                            const int* __restrict__ offs, int* __restrict__ fills,
                            int* __restrict__ tok_of, float* __restrict__ slotw) {
    int i = blockIdx.x * 256 + threadIdx.x;
    if (i < T * TOPK) {
        int e = topk_idx[i];
        int p = offs[e] + atomicAdd(&fills[e], 1);
        tok_of[p] = i >> 2;
        slotw[p] = topkw[i];
    }
}

// ---------------- MoE up (gathered, fused gate+up+silu) ----------------
__global__ void moe_up_kernel(const float* __restrict__ X, const float* __restrict__ eg,
                              const float* __restrict__ eu, const int* __restrict__ tok_of,
                              const int* __restrict__ offs, const int* __restrict__ counts,
                              float* __restrict__ abuf) {
    int e = blockIdx.z;
    int cnt = counts[e];
    int m0 = blockIdx.y * GT;
    if (m0 >= cnt) return;
    int base = offs[e];
    int n0 = blockIdx.x * GT;
    __shared__ float As[GKT][LDP];
    __shared__ float Bg[GKT][LDP];
    __shared__ float Bu[GKT][LDP];
    __shared__ int toks[GT];
    int tid = threadIdx.x;
    if (tid < GT) toks[tid] = (m0 + tid < cnt) ? tok_of[base + m0 + tid] : 0;
    __syncthreads();
    int tx = tid & 15, ty = tid >> 4;
    const float* wg = eg + (size_t)e * H * MI;
    const float* wu = eu + (size_t)e * H * MI;
    float cg[4][4] = {}, cu[4][4] = {};
    for (int k0 = 0; k0 < H; k0 += GKT) {
        for (int mm = ty; mm < GT; mm += 16)
            As[tx][mm] = X[(size_t)toks[mm] * H + k0 + tx];
        int nL = tid & 63;
        for (int kk = tid >> 6; kk < GKT; kk += 4) {
            Bg[kk][nL] = wg[(size_t)(k0 + kk) * MI + n0 + nL];
            Bu[kk][nL] = wu[(size_t)(k0 + kk) * MI + n0 + nL];
        }
        __syncthreads();
#pragma unroll
        for (int kk = 0; kk < GKT; ++kk) {
            float4 a4 = *(const float4*)&As[kk][ty * 4];
            float4 g4 = *(const float4*)&Bg[kk][tx * 4];
            float4 u4 = *(const float4*)&Bu[kk][tx * 4];
            float av[4] = {a4.x, a4.y, a4.z, a4.w};
            float gv[4] = {g4.x, g4.y, g4.z, g4.w};
            float uv[4] = {u4.x, u4.y, u4.z, u4.w};
#pragma unroll
            for (int i = 0; i < 4; ++i)
#pragma unroll
                for (int j = 0; j < 4; ++j) {
                    cg[i][j] += av[i] * gv[j];
                    cu[i][j] += av[i] * uv[j];
                }
        }
        __syncthreads();
    }
    for (int i = 0; i < 4; ++i) {
        int m = m0 + ty * 4 + i;
        if (m >= cnt) continue;
        float* orow = abuf + (size_t)(base + m) * MI + n0;
        for (int j = 0; j < 4; ++j) {
            float g = cg[i][j], u = cu[i][j];
            orow[tx * 4 + j] = g / (1.f + __expf(-g)) * u;
        }
    }
}

// ---------------- MoE down (scatter-add with routing weight) ----------------
__global__ void moe_down_kernel(const float* __restrict__ abuf, const float* __restrict__ ed,
                                const int* __restrict__ tok_of, const float* __restrict__ slotw,
                                const int* __restrict__ offs, const int* __restrict__ counts,
                                float* __restrict__ routed) {
    int e = blockIdx.z;
    int cnt = counts[e];
    int m0 = blockIdx.y * GT;
    if (m0 >= cnt) return;
    int base = offs[e];
    int n0 = blockIdx.x * GT;
    __shared__ float As[GKT][LDP];
    __shared__ float Bs[GKT][LDP];
    int tid = threadIdx.x;
    int tx = tid & 15, ty = tid >> 4;
    const float* wd = ed + (size_t)e * MI * H;
    float acc[4][4] = {};
    for (int k0 = 0; k0 < MI; k0 += GKT) {
        for (int mm = ty; mm < GT; mm += 16) {
            int m = m0 + mm;
            As[tx][mm] = (m < cnt) ? abuf[(size_t)(base + m) * MI + k0 + tx] : 0.f;
        }
        int nL = tid & 63;
        for (int kk = tid >> 6; kk < GKT; kk += 4)
            Bs[kk][nL] = wd[(size_t)(k0 + kk) * H + n0 + nL];
        __syncthreads();
#pragma unroll
        for (int kk = 0; kk < GKT; ++kk) {
            float4 a4 = *(const float4*)&As[kk][ty * 4];
            float4 b4 = *(const float4*)&Bs[kk][tx * 4];
            float av[4] = {a4.x, a4.y, a4.z, a4.w};
            float bv[4] = {b4.x, b4.y, b4.z, b4.w};
#pragma unroll
            for (int i = 0; i < 4; ++i)
#pragma unroll
                for (int j = 0; j < 4; ++j) acc[i][j] += av[i] * bv[j];
        }
        __syncthreads();
    }
    for (int i = 0; i < 4; ++i) {
        int m = m0 + ty * 4 + i;
        if (m >= cnt) continue;
        int tok = tok_of[base + m];
        float w = slotw[base + m];
        float* orow = routed + (size_t)tok * H + n0;
        for (int j = 0; j < 4; ++j) atomicAdd(&orow[tx * 4 + j], w * acc[i][j]);
    }
}

// ---------------- shared expert up (fused gate+up+silu, no gather) ----------------
__global__ void shared_up_kernel(const float* __restrict__ X, const float* __restrict__ Wg,
                                 const float* __restrict__ Wu, float* __restrict__ outb) {
    int m0 = blockIdx.y * GT, n0 = blockIdx.x * GT;
    __shared__ float As[GKT][LDP];
    __shared__ float Bg[GKT][LDP];
    __shared__ float Bu[GKT][LDP];
    int tid = threadIdx.x;
    int tx = tid & 15, ty = tid >> 4;
    float cg[4][4] = {}, cu[4][4] = {};
    for (int k0 = 0; k0 < H; k0 += GKT) {
        for (int mm = ty; mm < GT; mm += 16)
            As[tx][mm] = X[(size_t)(m0 + mm) * H + k0 + tx];
        int nL = tid & 63;
        for (int kk = tid >> 6; kk < GKT; kk += 4) {
            Bg[kk][nL] = Wg[(size_t)(k0 + kk) * SI + n0 + nL];
            Bu[kk][nL] = Wu[(size_t)(k0 + kk) * SI + n0 + nL];
        }
        __syncthreads();
#pragma unroll
        for (int kk = 0; kk < GKT; ++kk) {
            float4 a4 = *(const float4*)&As[kk][ty * 4];
            float4 g4 = *(const float4*)&Bg[kk][tx * 4];
            float4 u4 = *(const float4*)&Bu[kk][tx * 4];
            float av[4] = {a4.x, a4.y, a4.z, a4.w};
            float gv[4] = {g4.x, g4.y, g4.z, g4.w};
            float uv[4] = {u4.x, u4.y, u4.z, u4.w};
#pragma unroll
            for (int i = 0; i < 4; ++i)
#pragma unroll
                for (int j = 0; j < 4; ++j) {
                    cg[i][j] += av[i] * gv[j];
                    cu[i][j] += av[i] * uv[j];
                }
        }
        __syncthreads();
    }
    for (int i = 0; i < 4; ++i) {
        float* orow = outb + (size_t)(m0 + ty * 4 + i) * SI + n0;
        for (int j = 0; j < 4; ++j) {
            float g = cg[i][j], u = cu[i][j];
            orow[tx * 4 + j] = g / (1.f + __expf(-g)) * u;
        }
    }
}

// ---------------- launch ----------------
extern "C" void kernel_launch(void* const* d_in, const int* in_sizes, int n_in,
                              void* d_out, int out_size, void* d_ws, size_t ws_size,
                              hipStream_t stream) {
    const float* hidden = (const float*)d_in[0];
    const int* pos = (const int*)d_in[1];
    const float* ln1w = (const float*)d_in[2];
    const float* ln2w = (const float*)d_in[3];
    const float* q_w = (const float*)d_in[4];
    const float* k_w = (const float*)d_in[5];
    const float* v_w = (const float*)d_in[6];
    const float* o_w = (const float*)d_in[7];
    const float* router_w = (const float*)d_in[8];
    const float* router_b = (const float*)d_in[9];
    const float* eg_w = (const float*)d_in[10];
    const float* eu_w = (const float*)d_in[11];
    const float* ed_w = (const float*)d_in[12];
    const float* sg_w = (const float*)d_in[13];
    const float* su_w = (const float*)d_in[14];
    const float* sd_w = (const float*)d_in[15];
    float* out = (float*)d_out;

    float* f = (float*)d_ws;
    float* h_ln1 = f;  f += (size_t)T * H;       // also reused as attnp
    float* qb = f;     f += (size_t)T * H;       // also reused as h_ln2
    float* kb = f;     f += (size_t)T * NKV * HD;  // kb+vb reused as sharedo
    float* vb = f;     f += (size_t)T * NKV * HD;
    float* attno = f;  f += (size_t)T * H;       // also reused as ashared
    float* h2 = f;     f += (size_t)T * H;
    float* logits = f; f += (size_t)T * NE;
    float* topkw = f;  f += (size_t)T * TOPK;
    float* slotw = f;  f += (size_t)T * TOPK;
    float* abuf = f;   f += (size_t)T * TOPK * MI;
    float* routed = f; f += (size_t)T * H;
    int* topk_idx = (int*)f;
    int* counts = topk_idx + T * TOPK;
    int* fills = counts + NE;
    int* offs = fills + NE;
    int* tok_of = offs + NE;

    float* attnp = h_ln1;   // h_ln1 dead after q/k/v projections
    float* h_ln2 = qb;      // qb dead after attention
    float* ashared = attno; // attno dead after o-projection
    float* sharedo = kb;    // kb+vb (1M contiguous) dead after attention

    dim3 b256(256);

    rmsnorm_kernel<<<T, b256, 0, stream>>>(hidden, ln1w, h_ln1);
    gemm_kernel<true><<<dim3(H / GT, T / GT), b256, 0, stream>>>(h_ln1, q_w, qb, T, H, H);
    gemm_kernel<true><<<dim3((NKV * HD) / GT, T / GT), b256, 0, stream>>>(h_ln1, k_w, kb, T, NKV * HD, H);
    gemm_kernel<true><<<dim3((NKV * HD) / GT, T / GT), b256, 0, stream>>>(h_ln1, v_w, vb, T, NKV * HD, H);
    {
        int tot = T * NH * 64 + T * NKV * 64;
        rope_kernel<<<(tot + 255) / 256, b256, 0, stream>>>(qb, kb, pos);
    }
    attn_kernel<<<dim3(NH, T / 32), b256, 0, stream>>>(qb, kb, vb, attno);
    gemm_kernel<true><<<dim3(H / GT, T / GT), b256, 0, stream>>>(attno, o_w, attnp, T, H, H);
    add2_kernel<<<(T * H + 255) / 256, b256, 0, stream>>>(hidden, attnp, h2, T * H);
    rmsnorm_kernel<<<T, b256, 0, stream>>>(h2, ln2w, h_ln2);

    gemm_kernel<true><<<dim3(1, T / GT), b256, 0, stream>>>(h_ln2, router_w, logits, T, NE, H);
    router_kernel<<<(T + 255) / 256, b256, 0, stream>>>(logits, router_b, topk_idx, topkw);
    zero_i_kernel<<<1, b256, 0, stream>>>(counts, 2 * NE);  // counts + fills contiguous
    count_kernel<<<(T * TOPK + 255) / 256, b256, 0, stream>>>(topk_idx, counts);
    scan_kernel<<<1, 1, 0, stream>>>(counts, offs);
    fill_kernel<<<(T * TOPK + 255) / 256, b256, 0, stream>>>(topk_idx, topkw, offs, fills, tok_of, slotw);
    zero_f_kernel<<<(T * H + 255) / 256, b256, 0, stream>>>(routed, T * H);

    moe_up_kernel<<<dim3(MI / GT, (T * TOPK) / GT, NE), b256, 0, stream>>>(
        h_ln2, eg_w, eu_w, tok_of, offs, counts, abuf);
    moe_down_kernel<<<dim3(H / GT, (T * TOPK) / GT, NE), b256, 0, stream>>>(
        abuf, ed_w, tok_of, slotw, offs, counts, routed);

    shared_up_kernel<<<dim3(SI / GT, T / GT), b256, 0, stream>>>(h_ln2, sg_w, su_w, ashared);
    gemm_kernel<false><<<dim3(H / GT, T / GT), b256, 0, stream>>>(ashared, sd_w, sharedo, T, H, SI);

    add3_kernel<<<(T * H + 255) / 256, b256, 0, stream>>>(h2, routed, sharedo, out, T * H);
}

// Round 2
// 2113.842 us; speedup vs baseline: 1.3523x; 1.3523x over previous
//
#include <hip/hip_runtime.h>
#include <math.h>

#define T 1024
#define H 1024
#define NH 8
#define NKV 4
#define HD 128
#define NE 32
#define TOPK 4
#define NG 8
#define MI 512
#define SI 1024
#define RSF 2.5f
#define EPS 1e-6f

// small-GEMM (router) tile params
#define GT 64
#define GKT 16
#define LDP 68

// big-GEMM tile params
#define BK 16
#define LDB 132  // padded dword stride for 128-wide LDS tiles
#define LDD 68   // padded dword stride for 64-wide LDS tiles

// ---------------- elementwise / norm ----------------
__global__ void rmsnorm_kernel(const float* __restrict__ x, const float* __restrict__ w,
                               float* __restrict__ out) {
    int t = blockIdx.x;
    __shared__ float red[256];
    const float* xr = x + (size_t)t * H;
    float s = 0.f;
    for (int i = threadIdx.x; i < H; i += 256) { float v = xr[i]; s += v * v; }
    red[threadIdx.x] = s;
    __syncthreads();
    for (int st = 128; st > 0; st >>= 1) {
        if (threadIdx.x < st) red[threadIdx.x] += red[threadIdx.x + st];
        __syncthreads();
    }
    float inv = rsqrtf(red[0] / (float)H + EPS);
    float* orow = out + (size_t)t * H;
    for (int i = threadIdx.x; i < H; i += 256) orow[i] = xr[i] * inv * w[i];
}

__global__ void add2_kernel(const float* __restrict__ a, const float* __restrict__ b,
                            float* __restrict__ o, int n) {
    int i = blockIdx.x * 256 + threadIdx.x;
    if (i < n) o[i] = a[i] + b[i];
}

__global__ void zero_i_kernel(int* p, int n) {
    int i = blockIdx.x * 256 + threadIdx.x;
    if (i < n) p[i] = 0;
}

// ---------------- small tiled SGEMM (router only, handles N<64) ----------------
__global__ void gemm_small_bt(const float* __restrict__ A, const float* __restrict__ B,
                              float* __restrict__ C, int M, int N, int K) {
    __shared__ float As[GKT][LDP];
    __shared__ float Bs[GKT][LDP];
    int tid = threadIdx.x;
    int tx = tid & 15, ty = tid >> 4;
    int m0 = blockIdx.y * GT, n0 = blockIdx.x * GT;
    float acc[4][4] = {};
    for (int k0 = 0; k0 < K; k0 += GKT) {
        for (int mm = ty; mm < GT; mm += 16) {
            int gm = m0 + mm;
            As[tx][mm] = (gm < M) ? A[(size_t)gm * K + k0 + tx] : 0.f;
        }
        for (int nn = ty; nn < GT; nn += 16) {
            int gn = n0 + nn;
            Bs[tx][nn] = (gn < N) ? B[(size_t)gn * K + k0 + tx] : 0.f;
        }
        __syncthreads();
#pragma unroll
        for (int kk = 0; kk < GKT; ++kk) {
            float4 a4 = *(const float4*)&As[kk][ty * 4];
            float4 b4 = *(const float4*)&Bs[kk][tx * 4];
            float av[4] = {a4.x, a4.y, a4.z, a4.w};
            float bv[4] = {b4.x, b4.y, b4.z, b4.w};
#pragma unroll
            for (int i = 0; i < 4; ++i)
#pragma unroll
                for (int j = 0; j < 4; ++j) acc[i][j] += av[i] * bv[j];
        }
        __syncthreads();
    }
    for (int i = 0; i < 4; ++i) {
        int gm = m0 + ty * 4 + i;
        if (gm >= M) continue;
        for (int j = 0; j < 4; ++j) {
            int gn = n0 + tx * 4 + j;
            if (gn < N) C[(size_t)gm * N + gn] = acc[i][j];
        }
    }
}

// ---------------- big SGEMM: 128x128 tile, 8x8 micro (split 4+4) ----------------
// BT=true: B is (N,K) row-major (C=A@B^T). BT=false: B is (K,N) row-major.
// M,N,K all multiples of the tile — no bounds checks.
template <bool BT>
__global__ __launch_bounds__(256) void gemm128(const float* __restrict__ A,
                                               const float* __restrict__ B,
                                               float* __restrict__ C, int M, int N, int K) {
    __shared__ float As[BK][LDB];
    __shared__ float Bs[BK][LDB];
    int tid = threadIdx.x;
    int m0 = blockIdx.y * 128, n0 = blockIdx.x * 128;
    int tx = tid & 15, ty = tid >> 4;
    int mA = tid & 127, khA = tid >> 7;
    float acc[8][8] = {};
    for (int k0 = 0; k0 < K; k0 += BK) {
#pragma unroll
        for (int q = khA * 2; q < khA * 2 + 2; ++q) {
            float4 a = *(const float4*)&A[(size_t)(m0 + mA) * K + k0 + q * 4];
            As[q * 4 + 0][mA] = a.x; As[q * 4 + 1][mA] = a.y;
            As[q * 4 + 2][mA] = a.z; As[q * 4 + 3][mA] = a.w;
        }
        if (BT) {
#pragma unroll
            for (int q = khA * 2; q < khA * 2 + 2; ++q) {
                float4 b = *(const float4*)&B[(size_t)(n0 + mA) * K + k0 + q * 4];
                Bs[q * 4 + 0][mA] = b.x; Bs[q * 4 + 1][mA] = b.y;
                Bs[q * 4 + 2][mA] = b.z; Bs[q * 4 + 3][mA] = b.w;
            }
        } else {
            int nq = tid & 31, kk2 = tid >> 5;
#pragma unroll
            for (int kk = kk2 * 2; kk < kk2 * 2 + 2; ++kk)
                *(float4*)&Bs[kk][nq * 4] =
                    *(const float4*)&B[(size_t)(k0 + kk) * N + n0 + nq * 4];
        }
        __syncthreads();
#pragma unroll
        for (int kk = 0; kk < BK; ++kk) {
            float4 a0 = *(const float4*)&As[kk][ty * 4];
            float4 a1 = *(const float4*)&As[kk][64 + ty * 4];
            float4 b0 = *(const float4*)&Bs[kk][tx * 4];
            float4 b1 = *(const float4*)&Bs[kk][64 + tx * 4];
            float av[8] = {a0.x, a0.y, a0.z, a0.w, a1.x, a1.y, a1.z, a1.w};
            float bv[8] = {b0.x, b0.y, b0.z, b0.w, b1.x, b1.y, b1.z, b1.w};
#pragma unroll
            for (int i = 0; i < 8; ++i)
#pragma unroll
                for (int j = 0; j < 8; ++j) acc[i][j] += av[i] * bv[j];
        }
        __syncthreads();
    }
#pragma unroll
    for (int ih = 0; ih < 2; ++ih)
#pragma unroll
        for (int i = 0; i < 4; ++i) {
            int m = m0 + ih * 64 + ty * 4 + i;
#pragma unroll
            for (int jh = 0; jh < 2; ++jh) {
                float4 v = make_float4(acc[ih * 4 + i][jh * 4 + 0], acc[ih * 4 + i][jh * 4 + 1],
                                       acc[ih * 4 + i][jh * 4 + 2], acc[ih * 4 + i][jh * 4 + 3]);
                *(float4*)&C[(size_t)m * N + n0 + jh * 64 + tx * 4] = v;
            }
        }
}

// ---------------- rope ----------------
__global__ void rope_kernel(float* __restrict__ q, float* __restrict__ k,
                            const int* __restrict__ pos) {
    int i = blockIdx.x * 256 + threadIdx.x;
    const int totq = T * NH * 64;
    const int tot = totq + T * NKV * 64;
    if (i >= tot) return;
    float* buf;
    int t, hh, d, nh;
    if (i < totq) {
        buf = q; nh = NH;
        int r = i; d = r & 63; r >>= 6; hh = r % NH; t = r / NH;
    } else {
        buf = k; nh = NKV;
        int r = i - totq; d = r & 63; r >>= 6; hh = r % NKV; t = r / NKV;
    }
    float p = (float)pos[t];
    float inv = powf(10000.0f, -(float)d / 64.0f);
    float fr = p * inv;
    float sv, cv;
    sincosf(fr, &sv, &cv);
    size_t bi = ((size_t)t * nh + hh) * HD + d;
    float x1 = buf[bi], x2 = buf[bi + 64];
    buf[bi] = x1 * cv - x2 * sv;
    buf[bi + 64] = x2 * cv + x1 * sv;
}

// ---------------- flash attention (causal, GQA), vectorized, no serial softmax ---------
__global__ __launch_bounds__(256) void attn_kernel(const float* __restrict__ Q,
                                                   const float* __restrict__ Kb,
                                                   const float* __restrict__ Vb,
                                                   float* __restrict__ O) {
    int h = blockIdx.x;
    int qb = blockIdx.y;
    int kvh = h >> 1;  // rep = NH/NKV = 2
    __shared__ float Qs[32][129];
    __shared__ float Ks[32][129];
    __shared__ float Vs[32][129];
    __shared__ float Ss[32][33];
    int tid = threadIdx.x;
    int q0 = qb * 32;
    // stage Q tile (32x128) as float4
    for (int i = tid; i < 1024; i += 256) {
        int r = i >> 5, d4 = (i & 31) * 4;
        *(float4*)&Qs[r][d4] = *(const float4*)&Q[((size_t)(q0 + r) * NH + h) * HD + d4];
    }
    __syncthreads();
    int row = tid >> 3, seg = tid & 7;
    int c0 = seg * 4;
    float m_r = -1e30f, l_r = 0.f;
    float4 oa0 = make_float4(0, 0, 0, 0), oa1 = oa0, oa2 = oa0, oa3 = oa0;
    const float scale = 0.08838834764831845f;  // 1/sqrt(128)
    for (int k0 = 0; k0 <= q0; k0 += 32) {
        for (int i = tid; i < 1024; i += 256) {
            int r = i >> 5, d4 = (i & 31) * 4;
            *(float4*)&Ks[r][d4] = *(const float4*)&Kb[((size_t)(k0 + r) * NKV + kvh) * HD + d4];
            *(float4*)&Vs[r][d4] = *(const float4*)&Vb[((size_t)(k0 + r) * NKV + kvh) * HD + d4];
        }
        __syncthreads();
        // scores: this thread owns cols c0..c0+3 of its row
        float s0 = 0.f, s1 = 0.f, s2 = 0.f, s3 = 0.f;
#pragma unroll
        for (int dg = 0; dg < 32; ++dg) {
            float4 q4 = *(const float4*)&Qs[row][dg * 4];
            float4 k4;
            k4 = *(const float4*)&Ks[c0 + 0][dg * 4];
            s0 += q4.x * k4.x + q4.y * k4.y + q4.z * k4.z + q4.w * k4.w;
            k4 = *(const float4*)&Ks[c0 + 1][dg * 4];
            s1 += q4.x * k4.x + q4.y * k4.y + q4.z * k4.z + q4.w * k4.w;
            k4 = *(const float4*)&Ks[c0 + 2][dg * 4];
            s2 += q4.x * k4.x + q4.y * k4.y + q4.z * k4.z + q4.w * k4.w;
            k4 = *(const float4*)&Ks[c0 + 3][dg * 4];
            s3 += q4.x * k4.x + q4.y * k4.y + q4.z * k4.z + q4.w * k4.w;
        }
        s0 *= scale; s1 *= scale; s2 *= scale; s3 *= scale;
        int gr = q0 + row;
        if (k0 + c0 + 0 > gr) s0 = -1e30f;
        if (k0 + c0 + 1 > gr) s1 = -1e30f;
        if (k0 + c0 + 2 > gr) s2 = -1e30f;
        if (k0 + c0 + 3 > gr) s3 = -1e30f;
        // distributed row-softmax across the 8 lanes of this row (same wave)
        float mx = fmaxf(fmaxf(s0, s1), fmaxf(s2, s3));
#pragma unroll
        for (int off = 1; off < 8; off <<= 1) mx = fmaxf(mx, __shfl_xor(mx, off, 8));
        float mn = fmaxf(m_r, mx);
        float alpha = __expf(m_r - mn);
        float p0 = __expf(s0 - mn), p1 = __expf(s1 - mn);
        float p2 = __expf(s2 - mn), p3 = __expf(s3 - mn);
        float ps = p0 + p1 + p2 + p3;
#pragma unroll
        for (int off = 1; off < 8; off <<= 1) ps += __shfl_xor(ps, off, 8);
        l_r = l_r * alpha + ps;
        m_r = mn;
        Ss[row][c0 + 0] = p0; Ss[row][c0 + 1] = p1;
        Ss[row][c0 + 2] = p2; Ss[row][c0 + 3] = p3;
        __syncthreads();
        // rescale and accumulate PV; this thread owns d = seg*4 + 32*i, i=0..3
        oa0.x *= alpha; oa0.y *= alpha; oa0.z *= alpha; oa0.w *= alpha;
        oa1.x *= alpha; oa1.y *= alpha; oa1.z *= alpha; oa1.w *= alpha;
        oa2.x *= alpha; oa2.y *= alpha; oa2.z *= alpha; oa2.w *= alpha;
        oa3.x *= alpha; oa3.y *= alpha; oa3.z *= alpha; oa3.w *= alpha;
        int d0 = seg * 4;
#pragma unroll
        for (int c = 0; c < 32; ++c) {
            float p = Ss[row][c];
            float4 v4;
            v4 = *(const float4*)&Vs[c][d0];
            oa0.x += p * v4.x; oa0.y += p * v4.y; oa0.z += p * v4.z; oa0.w += p * v4.w;
            v4 = *(const float4*)&Vs[c][d0 + 32];
            oa1.x += p * v4.x; oa1.y += p * v4.y; oa1.z += p * v4.z; oa1.w += p * v4.w;
            v4 = *(const float4*)&Vs[c][d0 + 64];
            oa2.x += p * v4.x; oa2.y += p * v4.y; oa2.z += p * v4.z; oa2.w += p * v4.w;
            v4 = *(const float4*)&Vs[c][d0 + 96];
            oa3.x += p * v4.x; oa3.y += p * v4.y; oa3.z += p * v4.z; oa3.w += p * v4.w;
        }
        __syncthreads();
    }
    float li = 1.f / l_r;
    size_t ob = ((size_t)(q0 + row) * NH + h) * HD + seg * 4;
    *(float4*)&O[ob]      = make_float4(oa0.x * li, oa0.y * li, oa0.z * li, oa0.w * li);
    *(float4*)&O[ob + 32] = make_float4(oa1.x * li, oa1.y * li, oa1.z * li, oa1.w * li);
    *(float4*)&O[ob + 64] = make_float4(oa2.x * li, oa2.y * li, oa2.z * li, oa2.w * li);
    *(float4*)&O[ob + 96] = make_float4(oa3.x * li, oa3.y * li, oa3.z * li, oa3.w * li);
}

// ---------------- router ----------------
__global__ void router_kernel(const float* __restrict__ logits, const float* __restrict__ bias,
                              int* __restrict__ topk_idx, float* __restrict__ topkw) {
    int t = blockIdx.x * 256 + threadIdx.x;
    if (t >= T) return;
    float sc[NE], sfc[NE];
    for (int e = 0; e < NE; ++e) {
        float s = 1.f / (1.f + expf(-logits[(size_t)t * NE + e]));
        sc[e] = s;
        sfc[e] = s + bias[e];
    }
    float gs[NG];
    for (int g = 0; g < NG; ++g) {
        float m1 = -1e30f, m2 = -1e30f;
        for (int i = 0; i < 4; ++i) {
            float v = sfc[g * 4 + i];
            if (v > m1) { m2 = m1; m1 = v; }
            else if (v > m2) m2 = v;
        }
        gs[g] = m1 + m2;
    }
    bool gmask[NG];
    for (int g = 0; g < NG; ++g) gmask[g] = false;
    for (int r = 0; r < 4; ++r) {
        int bi = 0; float bv = -1e30f;
        for (int g = 0; g < NG; ++g)
            if (gs[g] > bv) { bv = gs[g]; bi = g; }
        gmask[bi] = true;
        gs[bi] = -1e30f;
    }
    float msfc[NE];
    for (int e = 0; e < NE; ++e) msfc[e] = gmask[e >> 2] ? sfc[e] : 0.f;
    int idx[TOPK]; float w[TOPK]; float wsum = 0.f;
    for (int r = 0; r < TOPK; ++r) {
        int bi = 0; float bv = -1e30f;
        for (int e = 0; e < NE; ++e)
            if (msfc[e] > bv) { bv = msfc[e]; bi = e; }
        idx[r] = bi;
        msfc[bi] = -1e30f;
        w[r] = sc[bi];
        wsum += w[r];
    }
    float inv = RSF / (wsum + 1e-20f);
    for (int r = 0; r < TOPK; ++r) {
        topk_idx[(size_t)t * TOPK + r] = idx[r];
        topkw[(size_t)t * TOPK + r] = w[r] * inv;
    }
}

__global__ void count_kernel(const int* __restrict__ topk_idx, int* __restrict__ counts) {
    int i = blockIdx.x * 256 + threadIdx.x;
    if (i < T * TOPK) atomicAdd(&counts[topk_idx[i]], 1);
}
__global__ void scan_kernel(const int* __restrict__ counts, int* __restrict__ offs) {
    if (threadIdx.x == 0 && blockIdx.x == 0) {
        int acc = 0;
        for (int e = 0; e < NE; ++e) { offs[e] = acc; acc += counts[e]; }
    }
}
__global__ void fill_kernel(const int* __restrict__ topk_idx,
                            const int* __restrict__ offs, int* __restrict__ fills,
                            int* __restrict__ tok_of, int* __restrict__ slot_of) {
    int i = blockIdx.x * 256 + threadIdx.x;
    if (i < T * TOPK) {
        int e = topk_idx[i];
        int p = offs[e] + atomicAdd(&fills[e], 1);
        tok_of[p] = i >> 2;
        slot_of[i] = p;
    }
}

// ---------------- MoE up (gathered dual GEMM, 128x64 tile, silu epilogue) -------------
__global__ __launch_bounds__(256) void moe_up_kernel(
    const float* __restrict__ X, const float* __restrict__ eg, const float* __restrict__ eu,
    const int* __restrict__ tok_of, const int* __restrict__ offs,
    const int* __restrict__ counts, float* __restrict__ abuf) {
    int e = blockIdx.z;
    int cnt = counts[e];
    int m0 = blockIdx.y * 128;
    if (m0 >= cnt) return;
    int base = offs[e];
    int n0 = blockIdx.x * 64;
    __shared__ float As[BK][LDB];
    __shared__ float Bg[BK][LDD];
    __shared__ float Bu[BK][LDD];
    __shared__ int toks[128];
    int tid = threadIdx.x;
    if (tid < 128) {
        int slot = base + m0 + tid;
        toks[tid] = tok_of[slot > T * TOPK - 1 ? T * TOPK - 1 : slot];
    }
    __syncthreads();
    int tx = tid & 15, ty = tid >> 4;
    int mA = tid & 127, khA = tid >> 7;
    int nqB = tid & 15, kkB = tid >> 4;
    const float* wg = eg + (size_t)e * H * MI;
    const float* wu = eu + (size_t)e * H * MI;
    float ag[8][4] = {}, au[8][4] = {};
    for (int k0 = 0; k0 < H; k0 += BK) {
#pragma unroll
        for (int q = khA * 2; q < khA * 2 + 2; ++q) {
            float4 a = *(const float4*)&X[(size_t)toks[mA] * H + k0 + q * 4];
            As[q * 4 + 0][mA] = a.x; As[q * 4 + 1][mA] = a.y;
            As[q * 4 + 2][mA] = a.z; As[q * 4 + 3][mA] = a.w;
        }
        *(float4*)&Bg[kkB][nqB * 4] = *(const float4*)&wg[(size_t)(k0 + kkB) * MI + n0 + nqB * 4];
        *(float4*)&Bu[kkB][nqB * 4] = *(const float4*)&wu[(size_t)(k0 + kkB) * MI + n0 + nqB * 4];
        __syncthreads();
#pragma unroll
        for (int kk = 0; kk < BK; ++kk) {
            float4 a0 = *(const float4*)&As[kk][ty * 4];
            float4 a1 = *(const float4*)&As[kk][64 + ty * 4];
            float4 g0 = *(const float4*)&Bg[kk][tx * 4];
            float4 u0 = *(const float4*)&Bu[kk][tx * 4];
            float av[8] = {a0.x, a0.y, a0.z, a0.w, a1.x, a1.y, a1.z, a1.w};
            float gv[4] = {g0.x, g0.y, g0.z, g0.w};
            float uv[4] = {u0.x, u0.y, u0.z, u0.w};
#pragma unroll
            for (int i = 0; i < 8; ++i)
#pragma unroll
                for (int j = 0; j < 4; ++j) {
                    ag[i][j] += av[i] * gv[j];
                    au[i][j] += av[i] * uv[j];
                }
        }
        __syncthreads();
    }
#pragma unroll
    for (int ih = 0; ih < 2; ++ih)
#pragma unroll
        for (int i = 0; i < 4; ++i) {
            int m = m0 + ih * 64 + ty * 4 + i;
            if (m >= cnt) continue;
            float* orow = abuf + (size_t)(base + m) * MI + n0 + tx * 4;
            float4 v;
            float g, u;
            g = ag[ih * 4 + i][0]; u = au[ih * 4 + i][0]; v.x = g / (1.f + __expf(-g)) * u;
            g = ag[ih * 4 + i][1]; u = au[ih * 4 + i][1]; v.y = g / (1.f + __expf(-g)) * u;
            g = ag[ih * 4 + i][2]; u = au[ih * 4 + i][2]; v.z = g / (1.f + __expf(-g)) * u;
            g = ag[ih * 4 + i][3]; u = au[ih * 4 + i][3]; v.w = g / (1.f + __expf(-g)) * u;
            *(float4*)orow = v;
        }
}

// ---------------- MoE down (per-slot output, no atomics) ----------------
__global__ __launch_bounds__(256) void moe_down_kernel(
    const float* __restrict__ abuf, const float* __restrict__ ed,
    const int* __restrict__ offs, const int* __restrict__ counts,
    float* __restrict__ o_slot) {
    int e = blockIdx.z;
    int cnt = counts[e];
    int m0 = blockIdx.y * 128;
    if (m0 >= cnt) return;
    int base = offs[e];
    int n0 = blockIdx.x * 128;
    __shared__ float As[BK][LDB];
    __shared__ float Bs[BK][LDB];
    int tid = threadIdx.x;
    int tx = tid & 15, ty = tid >> 4;
    int mA = tid & 127, khA = tid >> 7;
    const float* Arows = abuf + (size_t)base * MI;
    const float* wd = ed + (size_t)e * MI * H;
    float acc[8][8] = {};
    for (int k0 = 0; k0 < MI; k0 += BK) {
#pragma unroll
        for (int q = khA * 2; q < khA * 2 + 2; ++q) {
            float4 a = *(const float4*)&Arows[(size_t)(m0 + mA) * MI + k0 + q * 4];
            As[q * 4 + 0][mA] = a.x; As[q * 4 + 1][mA] = a.y;
            As[q * 4 + 2][mA] = a.z; As[q * 4 + 3][mA] = a.w;
        }
        int nq = tid & 31, kk2 = tid >> 5;
#pragma unroll
        for (int kk = kk2 * 2; kk < kk2 * 2 + 2; ++kk)
            *(float4*)&Bs[kk][nq * 4] = *(const float4*)&wd[(size_t)(k0 + kk) * H + n0 + nq * 4];
        __syncthreads();
#pragma unroll
        for (int kk = 0; kk < BK; ++kk) {
            float4 a0 = *(const float4*)&As[kk][ty * 4];
            float4 a1 = *(const float4*)&As[kk][64 + ty * 4];
            float4 b0 = *(const float4*)&Bs[kk][tx * 4];
            float4 b1 = *(const float4*)&Bs[kk][64 + tx * 4];
            float av[8] = {a0.x, a0.y, a0.z, a0.w, a1.x, a1.y, a1.z, a1.w};
            float bv[8] = {b0.x, b0.y, b0.z, b0.w, b1.x, b1.y, b1.z, b1.w};
#pragma unroll
            for (int i = 0; i < 8; ++i)
#pragma unroll
                for (int j = 0; j < 8; ++j) acc[i][j] += av[i] * bv[j];
        }
        __syncthreads();
    }
#pragma unroll
    for (int ih = 0; ih < 2; ++ih)
#pragma unroll
        for (int i = 0; i < 4; ++i) {
            int m = m0 + ih * 64 + ty * 4 + i;
            if (m >= cnt) continue;
            float* orow = o_slot + (size_t)(base + m) * H + n0;
#pragma unroll
            for (int jh = 0; jh < 2; ++jh) {
                float4 v = make_float4(acc[ih * 4 + i][jh * 4 + 0], acc[ih * 4 + i][jh * 4 + 1],
                                       acc[ih * 4 + i][jh * 4 + 2], acc[ih * 4 + i][jh * 4 + 3]);
                *(float4*)&orow[jh * 64 + tx * 4] = v;
            }
        }
}

// ---------------- shared expert up (dual GEMM 128x64, silu epilogue) -----------------
__global__ __launch_bounds__(256) void shared_up_kernel(const float* __restrict__ X,
                                                        const float* __restrict__ Wg,
                                                        const float* __restrict__ Wu,
                                                        float* __restrict__ outb) {
    int m0 = blockIdx.y * 128, n0 = blockIdx.x * 64;
    __shared__ float As[BK][LDB];
    __shared__ float Bg[BK][LDD];
    __shared__ float Bu[BK][LDD];
    int tid = threadIdx.x;
    int tx = tid & 15, ty = tid >> 4;
    int mA = tid & 127, khA = tid >> 7;
    int nqB = tid & 15, kkB = tid >> 4;
    float ag[8][4] = {}, au[8][4] = {};
    for (int k0 = 0; k0 < H; k0 += BK) {
#pragma unroll
        for (int q = khA * 2; q < khA * 2 + 2; ++q) {
            float4 a = *(const float4*)&X[(size_t)(m0 + mA) * H + k0 + q * 4];
            As[q * 4 + 0][mA] = a.x; As[q * 4 + 1][mA] = a.y;
            As[q * 4 + 2][mA] = a.z; As[q * 4 + 3][mA] = a.w;
        }
        *(float4*)&Bg[kkB][nqB * 4] = *(const float4*)&Wg[(size_t)(k0 + kkB) * SI + n0 + nqB * 4];
        *(float4*)&Bu[kkB][nqB * 4] = *(const float4*)&Wu[(size_t)(k0 + kkB) * SI + n0 + nqB * 4];
        __syncthreads();
#pragma unroll
        for (int kk = 0; kk < BK; ++kk) {
            float4 a0 = *(const float4*)&As[kk][ty * 4];
            float4 a1 = *(const float4*)&As[kk][64 + ty * 4];
            float4 g0 = *(const float4*)&Bg[kk][tx * 4];
            float4 u0 = *(const float4*)&Bu[kk][tx * 4];
            float av[8] = {a0.x, a0.y, a0.z, a0.w, a1.x, a1.y, a1.z, a1.w};
            float gv[4] = {g0.x, g0.y, g0.z, g0.w};
            float uv[4] = {u0.x, u0.y, u0.z, u0.w};
#pragma unroll
            for (int i = 0; i < 8; ++i)
#pragma unroll
                for (int j = 0; j < 4; ++j) {
                    ag[i][j] += av[i] * gv[j];
                    au[i][j] += av[i] * uv[j];
                }
        }
        __syncthreads();
    }
#pragma unroll
    for (int ih = 0; ih < 2; ++ih)
#pragma unroll
        for (int i = 0; i < 4; ++i) {
            int m = m0 + ih * 64 + ty * 4 + i;
            float* orow = outb + (size_t)m * SI + n0 + tx * 4;
            float4 v;
            float g, u;
            g = ag[ih * 4 + i][0]; u = au[ih * 4 + i][0]; v.x = g / (1.f + __expf(-g)) * u;
            g = ag[ih * 4 + i][1]; u = au[ih * 4 + i][1]; v.y = g / (1.f + __expf(-g)) * u;
            g = ag[ih * 4 + i][2]; u = au[ih * 4 + i][2]; v.z = g / (1.f + __expf(-g)) * u;
            g = ag[ih * 4 + i][3]; u = au[ih * 4 + i][3]; v.w = g / (1.f + __expf(-g)) * u;
            *(float4*)orow = v;
        }
}

// ---------------- final combine: out = h2 + shared + sum_r w_r * o_slot[slot(t,r)] -----
__global__ void combine_kernel(const float* __restrict__ o_slot, const int* __restrict__ slot_of,
                               const float* __restrict__ topkw, const float* __restrict__ h2,
                               const float* __restrict__ sharedo, float* __restrict__ out) {
    int t = blockIdx.x;
    int d = threadIdx.x * 4;
    float4 a = *(const float4*)&h2[(size_t)t * H + d];
    float4 b = *(const float4*)&sharedo[(size_t)t * H + d];
    float4 acc = make_float4(a.x + b.x, a.y + b.y, a.z + b.z, a.w + b.w);
#pragma unroll
    for (int r = 0; r < TOPK; ++r) {
        int s = slot_of[t * TOPK + r];
        float w = topkw[t * TOPK + r];
        float4 v = *(const float4*)&o_slot[(size_t)s * H + d];
        acc.x += w * v.x; acc.y += w * v.y; acc.z += w * v.z; acc.w += w * v.w;
    }
    *(float4*)&out[(size_t)t * H + d] = acc;
}

// ---------------- launch ----------------
extern "C" void kernel_launch(void* const* d_in, const int* in_sizes, int n_in,
                              void* d_out, int out_size, void* d_ws, size_t ws_size,
                              hipStream_t stream) {
    const float* hidden = (const float*)d_in[0];
    const int* pos = (const int*)d_in[1];
    const float* ln1w = (const float*)d_in[2];
    const float* ln2w = (const float*)d_in[3];
    const float* q_w = (const float*)d_in[4];
    const float* k_w = (const float*)d_in[5];
    const float* v_w = (const float*)d_in[6];
    const float* o_w = (const float*)d_in[7];
    const float* router_w = (const float*)d_in[8];
    const float* router_b = (const float*)d_in[9];
    const float* eg_w = (const float*)d_in[10];
    const float* eu_w = (const float*)d_in[11];
    const float* ed_w = (const float*)d_in[12];
    const float* sg_w = (const float*)d_in[13];
    const float* su_w = (const float*)d_in[14];
    const float* sd_w = (const float*)d_in[15];
    float* out = (float*)d_out;

    float* f = (float*)d_ws;
    float* h_ln1 = f;  f += (size_t)T * H;          // reused as attnp
    float* qb = f;     f += (size_t)T * H;          // reused as h_ln2
    float* kb = f;     f += (size_t)T * NKV * HD;   // kb+vb reused as sharedo
    float* vb = f;     f += (size_t)T * NKV * HD;
    float* attno = f;  f += (size_t)T * H;          // reused as ashared
    float* h2 = f;     f += (size_t)T * H;
    float* logits = f; f += (size_t)T * NE;
    float* topkw = f;  f += (size_t)T * TOPK;
    float* abuf = f;   f += (size_t)(T * TOPK + 128) * MI;  // +128-row slack for tile reads
    float* o_slot = f; f += (size_t)T * TOPK * H;
    int* topk_idx = (int*)f;
    int* counts = topk_idx + T * TOPK;
    int* fills = counts + NE;
    int* offs = fills + NE;
    int* tok_of = offs + NE;
    int* slot_of = tok_of + T * TOPK;

    float* attnp = h_ln1;   // h_ln1 dead after q/k/v projections
    float* h_ln2 = qb;      // qb dead after attention
    float* ashared = attno; // attno dead after o-projection
    float* sharedo = kb;    // kb+vb (1M floats contiguous) dead after attention

    dim3 b256(256);

    rmsnorm_kernel<<<T, b256, 0, stream>>>(hidden, ln1w, h_ln1);
    gemm128<true><<<dim3(H / 128, T / 128), b256, 0, stream>>>(h_ln1, q_w, qb, T, H, H);
    gemm128<true><<<dim3((NKV * HD) / 128, T / 128), b256, 0, stream>>>(h_ln1, k_w, kb, T, NKV * HD, H);
    gemm128<true><<<dim3((NKV * HD) / 128, T / 128), b256, 0, stream>>>(h_ln1, v_w, vb, T, NKV * HD, H);
    {
        int tot = T * NH * 64 + T * NKV * 64;
        rope_kernel<<<(tot + 255) / 256, b256, 0, stream>>>(qb, kb, pos);
    }
    attn_kernel<<<dim3(NH, T / 32), b256, 0, stream>>>(qb, kb, vb, attno);
    gemm128<true><<<dim3(H / 128, T / 128), b256, 0, stream>>>(attno, o_w, attnp, T, H, H);
    add2_kernel<<<(T * H + 255) / 256, b256, 0, stream>>>(hidden, attnp, h2, T * H);
    rmsnorm_kernel<<<T, b256, 0, stream>>>(h2, ln2w, h_ln2);

    gemm_small_bt<<<dim3(1, T / GT), b256, 0, stream>>>(h_ln2, router_w, logits, T, NE, H);
    router_kernel<<<(T + 255) / 256, b256, 0, stream>>>(logits, router_b, topk_idx, topkw);
    zero_i_kernel<<<1, b256, 0, stream>>>(counts, 2 * NE);  // counts + fills contiguous
    count_kernel<<<(T * TOPK + 255) / 256, b256, 0, stream>>>(topk_idx, counts);
    scan_kernel<<<1, 1, 0, stream>>>(counts, offs);
    fill_kernel<<<(T * TOPK + 255) / 256, b256, 0, stream>>>(topk_idx, offs, fills, tok_of, slot_of);

    moe_up_kernel<<<dim3(MI / 64, (T * TOPK) / 128, NE), b256, 0, stream>>>(
        h_ln2, eg_w, eu_w, tok_of, offs, counts, abuf);
    moe_down_kernel<<<dim3(H / 128, (T * TOPK) / 128, NE), b256, 0, stream>>>(
        abuf, ed_w, offs, counts, o_slot);

    shared_up_kernel<<<dim3(SI / 64, T / 128), b256, 0, stream>>>(h_ln2, sg_w, su_w, ashared);
    gemm128<false><<<dim3(H / 128, T / 128), b256, 0, stream>>>(ashared, sd_w, sharedo, T, H, SI);

    combine_kernel<<<T, b256, 0, stream>>>(o_slot, slot_of, topkw, h2, sharedo, out);
}

// Round 3
// 1126.822 us; speedup vs baseline: 2.5367x; 1.8759x over previous
//
#include <hip/hip_runtime.h>
#include <math.h>

#define T 1024
#define H 1024
#define NH 8
#define NKV 4
#define HD 128
#define NE 32
#define TOPK 4
#define NG 8
#define MI 512
#define SI 1024
#define RSF 2.5f
#define EPS 1e-6f

// small-GEMM (router) tile params
#define GT 64
#define GKT 16
#define LDP 68

// MFMA LDS tile: rows padded to 40 bf16 (80 B) -> b128 frag reads are 2-way-conflict only
#define KP 40

typedef short bf16x8 __attribute__((ext_vector_type(8)));
typedef float f32x4 __attribute__((ext_vector_type(4)));
#define MFMA16(a, b, c) __builtin_amdgcn_mfma_f32_16x16x32_bf16((a), (b), (c), 0, 0, 0)

__device__ inline unsigned short f2bf(float x) {
    unsigned u = __float_as_uint(x);
    u += 0x7fff + ((u >> 16) & 1);  // RNE
    return (unsigned short)(u >> 16);
}
__device__ inline float bf2f(unsigned short h) { return __uint_as_float(((unsigned)h) << 16); }

union U16S {
    unsigned short s[16];
    uint4 q[2];
};

// ---------------- elementwise / norm ----------------
__global__ void rmsnorm_kernel(const float* __restrict__ x, const float* __restrict__ w,
                               float* __restrict__ out) {
    int t = blockIdx.x;
    __shared__ float red[256];
    const float* xr = x + (size_t)t * H;
    float s = 0.f;
    for (int i = threadIdx.x; i < H; i += 256) { float v = xr[i]; s += v * v; }
    red[threadIdx.x] = s;
    __syncthreads();
    for (int st = 128; st > 0; st >>= 1) {
        if (threadIdx.x < st) red[threadIdx.x] += red[threadIdx.x + st];
        __syncthreads();
    }
    float inv = rsqrtf(red[0] / (float)H + EPS);
    float* orow = out + (size_t)t * H;
    for (int i = threadIdx.x; i < H; i += 256) orow[i] = xr[i] * inv * w[i];
}

__global__ void rmsnorm_dual_kernel(const float* __restrict__ x, const float* __restrict__ w,
                                    float* __restrict__ outf, unsigned short* __restrict__ outb) {
    int t = blockIdx.x;
    __shared__ float red[256];
    const float* xr = x + (size_t)t * H;
    float s = 0.f;
    for (int i = threadIdx.x; i < H; i += 256) { float v = xr[i]; s += v * v; }
    red[threadIdx.x] = s;
    __syncthreads();
    for (int st = 128; st > 0; st >>= 1) {
        if (threadIdx.x < st) red[threadIdx.x] += red[threadIdx.x + st];
        __syncthreads();
    }
    float inv = rsqrtf(red[0] / (float)H + EPS);
    for (int i = threadIdx.x; i < H; i += 256) {
        float v = xr[i] * inv * w[i];
        outf[(size_t)t * H + i] = v;
        outb[(size_t)t * H + i] = f2bf(v);
    }
}

__global__ void zero_i_kernel(int* p, int n) {
    int i = blockIdx.x * 256 + threadIdx.x;
    if (i < n) p[i] = 0;
}

// ---------------- small tiled SGEMM (router only, fp32 exact path) ----------------
__global__ void gemm_small_bt(const float* __restrict__ A, const float* __restrict__ B,
                              float* __restrict__ C, int M, int N, int K) {
    __shared__ float As[GKT][LDP];
    __shared__ float Bs[GKT][LDP];
    int tid = threadIdx.x;
    int tx = tid & 15, ty = tid >> 4;
    int m0 = blockIdx.y * GT, n0 = blockIdx.x * GT;
    float acc[4][4] = {};
    for (int k0 = 0; k0 < K; k0 += GKT) {
        for (int mm = ty; mm < GT; mm += 16) {
            int gm = m0 + mm;
            As[tx][mm] = (gm < M) ? A[(size_t)gm * K + k0 + tx] : 0.f;
        }
        for (int nn = ty; nn < GT; nn += 16) {
            int gn = n0 + nn;
            Bs[tx][nn] = (gn < N) ? B[(size_t)gn * K + k0 + tx] : 0.f;
        }
        __syncthreads();
#pragma unroll
        for (int kk = 0; kk < GKT; ++kk) {
            float4 a4 = *(const float4*)&As[kk][ty * 4];
            float4 b4 = *(const float4*)&Bs[kk][tx * 4];
            float av[4] = {a4.x, a4.y, a4.z, a4.w};
            float bv[4] = {b4.x, b4.y, b4.z, b4.w};
#pragma unroll
            for (int i = 0; i < 4; ++i)
#pragma unroll
                for (int j = 0; j < 4; ++j) acc[i][j] += av[i] * bv[j];
        }
        __syncthreads();
    }
    for (int i = 0; i < 4; ++i) {
        int gm = m0 + ty * 4 + i;
        if (gm >= M) continue;
        for (int j = 0; j < 4; ++j) {
            int gn = n0 + tx * 4 + j;
            if (gn < N) C[(size_t)gm * N + gn] = acc[i][j];
        }
    }
}

// ---------------- compensated bf16 MFMA GEMM, BT weights (N x K), fused QKV -----------
// 128x128 tile, 4 waves each 64x64, A and W split hi/lo: AhWh + AhWl + AlWh.
__global__ __launch_bounds__(256) void gemm_qkv_mfma(const float* __restrict__ X,
                                                     const float* __restrict__ qw,
                                                     const float* __restrict__ kw,
                                                     const float* __restrict__ vw,
                                                     float* __restrict__ qo,
                                                     float* __restrict__ ko,
                                                     float* __restrict__ vo) {
    __shared__ short Ah[128][KP], Al[128][KP], Bh[128][KP], Bl[128][KP];
    int tid = threadIdx.x;
    int m0 = blockIdx.y * 128;
    int n0 = blockIdx.x * 128;
    const float* W;
    float* O;
    int ldo, nc0;
    if (n0 < 1024) { nc0 = n0; W = qw; O = qo; ldo = H; }
    else if (n0 < 1536) { nc0 = n0 - 1024; W = kw; O = ko; ldo = NKV * HD; }
    else { nc0 = n0 - 1536; W = vw; O = vo; ldo = NKV * HD; }
    W += (size_t)nc0 * H;
    int r = tid & 127, kq = tid >> 7;
    int wave = tid >> 6, lane = tid & 63;
    int wm = (wave >> 1) * 64, wn = (wave & 1) * 64, lr = lane & 15, lq = lane >> 4;
    f32x4 acc[4][4];
#pragma unroll
    for (int i = 0; i < 4; ++i)
#pragma unroll
        for (int j = 0; j < 4; ++j) acc[i][j] = (f32x4){0.f, 0.f, 0.f, 0.f};
    for (int k0 = 0; k0 < H; k0 += 32) {
        // stage A (split)
        {
            const float* src = X + (size_t)(m0 + r) * H + k0 + kq * 16;
            U16S hi, lo;
#pragma unroll
            for (int j4 = 0; j4 < 4; ++j4) {
                float4 v = *(const float4*)(src + j4 * 4);
                float vv[4] = {v.x, v.y, v.z, v.w};
#pragma unroll
                for (int j = 0; j < 4; ++j) {
                    unsigned short h = f2bf(vv[j]);
                    hi.s[j4 * 4 + j] = h;
                    lo.s[j4 * 4 + j] = f2bf(vv[j] - bf2f(h));
                }
            }
            *(uint4*)&Ah[r][kq * 16] = hi.q[0];
            *(uint4*)&Ah[r][kq * 16 + 8] = hi.q[1];
            *(uint4*)&Al[r][kq * 16] = lo.q[0];
            *(uint4*)&Al[r][kq * 16 + 8] = lo.q[1];
        }
        // stage W (split) — BT layout: rows are output cols
        {
            const float* src = W + (size_t)r * H + k0 + kq * 16;
            U16S hi, lo;
#pragma unroll
            for (int j4 = 0; j4 < 4; ++j4) {
                float4 v = *(const float4*)(src + j4 * 4);
                float vv[4] = {v.x, v.y, v.z, v.w};
#pragma unroll
                for (int j = 0; j < 4; ++j) {
                    unsigned short h = f2bf(vv[j]);
                    hi.s[j4 * 4 + j] = h;
                    lo.s[j4 * 4 + j] = f2bf(vv[j] - bf2f(h));
                }
            }
            *(uint4*)&Bh[r][kq * 16] = hi.q[0];
            *(uint4*)&Bh[r][kq * 16 + 8] = hi.q[1];
            *(uint4*)&Bl[r][kq * 16] = lo.q[0];
            *(uint4*)&Bl[r][kq * 16 + 8] = lo.q[1];
        }
        __syncthreads();
        bf16x8 ah[4], al[4], bh[4], bl[4];
#pragma unroll
        for (int mt = 0; mt < 4; ++mt) {
            ah[mt] = *(const bf16x8*)&Ah[wm + mt * 16 + lr][lq * 8];
            al[mt] = *(const bf16x8*)&Al[wm + mt * 16 + lr][lq * 8];
        }
#pragma unroll
        for (int nt = 0; nt < 4; ++nt) {
            bh[nt] = *(const bf16x8*)&Bh[wn + nt * 16 + lr][lq * 8];
            bl[nt] = *(const bf16x8*)&Bl[wn + nt * 16 + lr][lq * 8];
        }
#pragma unroll
        for (int mt = 0; mt < 4; ++mt)
#pragma unroll
            for (int nt = 0; nt < 4; ++nt) {
                acc[mt][nt] = MFMA16(ah[mt], bh[nt], acc[mt][nt]);
                acc[mt][nt] = MFMA16(ah[mt], bl[nt], acc[mt][nt]);
                acc[mt][nt] = MFMA16(al[mt], bh[nt], acc[mt][nt]);
            }
        __syncthreads();
    }
#pragma unroll
    for (int mt = 0; mt < 4; ++mt)
#pragma unroll
        for (int nt = 0; nt < 4; ++nt)
#pragma unroll
            for (int p = 0; p < 4; ++p) {
                int m = m0 + wm + mt * 16 + lq * 4 + p;
                int col = nc0 + wn + nt * 16 + lr;
                O[(size_t)m * ldo + col] = acc[mt][nt][p];
            }
}

// ---------------- compensated bf16 MFMA GEMM, single BT weight + residual add --------
__global__ __launch_bounds__(256) void gemm_bt_res_mfma(const float* __restrict__ X,
                                                        const float* __restrict__ Wm,
                                                        const float* __restrict__ res,
                                                        float* __restrict__ O) {
    __shared__ short Ah[128][KP], Al[128][KP], Bh[128][KP], Bl[128][KP];
    int tid = threadIdx.x;
    int m0 = blockIdx.y * 128;
    int n0 = blockIdx.x * 128;
    const float* W = Wm + (size_t)n0 * H;
    int r = tid & 127, kq = tid >> 7;
    int wave = tid >> 6, lane = tid & 63;
    int wm = (wave >> 1) * 64, wn = (wave & 1) * 64, lr = lane & 15, lq = lane >> 4;
    f32x4 acc[4][4];
#pragma unroll
    for (int i = 0; i < 4; ++i)
#pragma unroll
        for (int j = 0; j < 4; ++j) acc[i][j] = (f32x4){0.f, 0.f, 0.f, 0.f};
    for (int k0 = 0; k0 < H; k0 += 32) {
        {
            const float* src = X + (size_t)(m0 + r) * H + k0 + kq * 16;
            U16S hi, lo;
#pragma unroll
            for (int j4 = 0; j4 < 4; ++j4) {
                float4 v = *(const float4*)(src + j4 * 4);
                float vv[4] = {v.x, v.y, v.z, v.w};
#pragma unroll
                for (int j = 0; j < 4; ++j) {
                    unsigned short h = f2bf(vv[j]);
                    hi.s[j4 * 4 + j] = h;
                    lo.s[j4 * 4 + j] = f2bf(vv[j] - bf2f(h));
                }
            }
            *(uint4*)&Ah[r][kq * 16] = hi.q[0];
            *(uint4*)&Ah[r][kq * 16 + 8] = hi.q[1];
            *(uint4*)&Al[r][kq * 16] = lo.q[0];
            *(uint4*)&Al[r][kq * 16 + 8] = lo.q[1];
        }
        {
            const float* src = W + (size_t)r * H + k0 + kq * 16;
            U16S hi, lo;
#pragma unroll
            for (int j4 = 0; j4 < 4; ++j4) {
                float4 v = *(const float4*)(src + j4 * 4);
                float vv[4] = {v.x, v.y, v.z, v.w};
#pragma unroll
                for (int j = 0; j < 4; ++j) {
                    unsigned short h = f2bf(vv[j]);
                    hi.s[j4 * 4 + j] = h;
                    lo.s[j4 * 4 + j] = f2bf(vv[j] - bf2f(h));
                }
            }
            *(uint4*)&Bh[r][kq * 16] = hi.q[0];
            *(uint4*)&Bh[r][kq * 16 + 8] = hi.q[1];
            *(uint4*)&Bl[r][kq * 16] = lo.q[0];
            *(uint4*)&Bl[r][kq * 16 + 8] = lo.q[1];
        }
        __syncthreads();
        bf16x8 ah[4], al[4], bh[4], bl[4];
#pragma unroll
        for (int mt = 0; mt < 4; ++mt) {
            ah[mt] = *(const bf16x8*)&Ah[wm + mt * 16 + lr][lq * 8];
            al[mt] = *(const bf16x8*)&Al[wm + mt * 16 + lr][lq * 8];
        }
#pragma unroll
        for (int nt = 0; nt < 4; ++nt) {
            bh[nt] = *(const bf16x8*)&Bh[wn + nt * 16 + lr][lq * 8];
            bl[nt] = *(const bf16x8*)&Bl[wn + nt * 16 + lr][lq * 8];
        }
#pragma unroll
        for (int mt = 0; mt < 4; ++mt)
#pragma unroll
            for (int nt = 0; nt < 4; ++nt) {
                acc[mt][nt] = MFMA16(ah[mt], bh[nt], acc[mt][nt]);
                acc[mt][nt] = MFMA16(ah[mt], bl[nt], acc[mt][nt]);
                acc[mt][nt] = MFMA16(al[mt], bh[nt], acc[mt][nt]);
            }
        __syncthreads();
    }
#pragma unroll
    for (int mt = 0; mt < 4; ++mt)
#pragma unroll
        for (int nt = 0; nt < 4; ++nt)
#pragma unroll
            for (int p = 0; p < 4; ++p) {
                int m = m0 + wm + mt * 16 + lq * 4 + p;
                int col = n0 + wn + nt * 16 + lr;
                O[(size_t)m * H + col] = res[(size_t)m * H + col] + acc[mt][nt][p];
            }
}

// ---------------- rope ----------------
__global__ void rope_kernel(float* __restrict__ q, float* __restrict__ k,
                            const int* __restrict__ pos) {
    int i = blockIdx.x * 256 + threadIdx.x;
    const int totq = T * NH * 64;
    const int tot = totq + T * NKV * 64;
    if (i >= tot) return;
    float* buf;
    int t, hh, d, nh;
    if (i < totq) {
        buf = q; nh = NH;
        int r = i; d = r & 63; r >>= 6; hh = r % NH; t = r / NH;
    } else {
        buf = k; nh = NKV;
        int r = i - totq; d = r & 63; r >>= 6; hh = r % NKV; t = r / NKV;
    }
    float p = (float)pos[t];
    float inv = powf(10000.0f, -(float)d / 64.0f);
    float fr = p * inv;
    float sv, cv;
    sincosf(fr, &sv, &cv);
    size_t bi = ((size_t)t * nh + hh) * HD + d;
    float x1 = buf[bi], x2 = buf[bi + 64];
    buf[bi] = x1 * cv - x2 * sv;
    buf[bi + 64] = x2 * cv + x1 * sv;
}

// ---------------- flash attention (causal, GQA), fp32 ----------------
__global__ __launch_bounds__(256) void attn_kernel(const float* __restrict__ Q,
                                                   const float* __restrict__ Kb,
                                                   const float* __restrict__ Vb,
                                                   float* __restrict__ O) {
    int h = blockIdx.x;
    int qb = blockIdx.y;
    int kvh = h >> 1;
    __shared__ float Qs[32][129];
    __shared__ float Ks[32][129];
    __shared__ float Vs[32][129];
    __shared__ float Ss[32][33];
    int tid = threadIdx.x;
    int q0 = qb * 32;
    for (int i = tid; i < 1024; i += 256) {
        int r = i >> 5, d4 = (i & 31) * 4;
        *(float4*)&Qs[r][d4] = *(const float4*)&Q[((size_t)(q0 + r) * NH + h) * HD + d4];
    }
    __syncthreads();
    int row = tid >> 3, seg = tid & 7;
    int c0 = seg * 4;
    float m_r = -1e30f, l_r = 0.f;
    float4 oa0 = make_float4(0, 0, 0, 0), oa1 = oa0, oa2 = oa0, oa3 = oa0;
    const float scale = 0.08838834764831845f;
    for (int k0 = 0; k0 <= q0; k0 += 32) {
        for (int i = tid; i < 1024; i += 256) {
            int r = i >> 5, d4 = (i & 31) * 4;
            *(float4*)&Ks[r][d4] = *(const float4*)&Kb[((size_t)(k0 + r) * NKV + kvh) * HD + d4];
            *(float4*)&Vs[r][d4] = *(const float4*)&Vb[((size_t)(k0 + r) * NKV + kvh) * HD + d4];
        }
        __syncthreads();
        float s0 = 0.f, s1 = 0.f, s2 = 0.f, s3 = 0.f;
#pragma unroll
        for (int dg = 0; dg < 32; ++dg) {
            float4 q4 = *(const float4*)&Qs[row][dg * 4];
            float4 k4;
            k4 = *(const float4*)&Ks[c0 + 0][dg * 4];
            s0 += q4.x * k4.x + q4.y * k4.y + q4.z * k4.z + q4.w * k4.w;
            k4 = *(const float4*)&Ks[c0 + 1][dg * 4];
            s1 += q4.x * k4.x + q4.y * k4.y + q4.z * k4.z + q4.w * k4.w;
            k4 = *(const float4*)&Ks[c0 + 2][dg * 4];
            s2 += q4.x * k4.x + q4.y * k4.y + q4.z * k4.z + q4.w * k4.w;
            k4 = *(const float4*)&Ks[c0 + 3][dg * 4];
            s3 += q4.x * k4.x + q4.y * k4.y + q4.z * k4.z + q4.w * k4.w;
        }
        s0 *= scale; s1 *= scale; s2 *= scale; s3 *= scale;
        int gr = q0 + row;
        if (k0 + c0 + 0 > gr) s0 = -1e30f;
        if (k0 + c0 + 1 > gr) s1 = -1e30f;
        if (k0 + c0 + 2 > gr) s2 = -1e30f;
        if (k0 + c0 + 3 > gr) s3 = -1e30f;
        float mx = fmaxf(fmaxf(s0, s1), fmaxf(s2, s3));
#pragma unroll
        for (int off = 1; off < 8; off <<= 1) mx = fmaxf(mx, __shfl_xor(mx, off, 8));
        float mn = fmaxf(m_r, mx);
        float alpha = __expf(m_r - mn);
        float p0 = __expf(s0 - mn), p1 = __expf(s1 - mn);
        float p2 = __expf(s2 - mn), p3 = __expf(s3 - mn);
        float ps = p0 + p1 + p2 + p3;
#pragma unroll
        for (int off = 1; off < 8; off <<= 1) ps += __shfl_xor(ps, off, 8);
        l_r = l_r * alpha + ps;
        m_r = mn;
        Ss[row][c0 + 0] = p0; Ss[row][c0 + 1] = p1;
        Ss[row][c0 + 2] = p2; Ss[row][c0 + 3] = p3;
        __syncthreads();
        oa0.x *= alpha; oa0.y *= alpha; oa0.z *= alpha; oa0.w *= alpha;
        oa1.x *= alpha; oa1.y *= alpha; oa1.z *= alpha; oa1.w *= alpha;
        oa2.x *= alpha; oa2.y *= alpha; oa2.z *= alpha; oa2.w *= alpha;
        oa3.x *= alpha; oa3.y *= alpha; oa3.z *= alpha; oa3.w *= alpha;
        int d0 = seg * 4;
#pragma unroll
        for (int c = 0; c < 32; ++c) {
            float p = Ss[row][c];
            float4 v4;
            v4 = *(const float4*)&Vs[c][d0];
            oa0.x += p * v4.x; oa0.y += p * v4.y; oa0.z += p * v4.z; oa0.w += p * v4.w;
            v4 = *(const float4*)&Vs[c][d0 + 32];
            oa1.x += p * v4.x; oa1.y += p * v4.y; oa1.z += p * v4.z; oa1.w += p * v4.w;
            v4 = *(const float4*)&Vs[c][d0 + 64];
            oa2.x += p * v4.x; oa2.y += p * v4.y; oa2.z += p * v4.z; oa2.w += p * v4.w;
            v4 = *(const float4*)&Vs[c][d0 + 96];
            oa3.x += p * v4.x; oa3.y += p * v4.y; oa3.z += p * v4.z; oa3.w += p * v4.w;
        }
        __syncthreads();
    }
    float li = 1.f / l_r;
    size_t ob = ((size_t)(q0 + row) * NH + h) * HD + seg * 4;
    *(float4*)&O[ob]      = make_float4(oa0.x * li, oa0.y * li, oa0.z * li, oa0.w * li);
    *(float4*)&O[ob + 32] = make_float4(oa1.x * li, oa1.y * li, oa1.z * li, oa1.w * li);
    *(float4*)&O[ob + 64] = make_float4(oa2.x * li, oa2.y * li, oa2.z * li, oa2.w * li);
    *(float4*)&O[ob + 96] = make_float4(oa3.x * li, oa3.y * li, oa3.z * li, oa3.w * li);
}

// ---------------- router ----------------
__global__ void router_kernel(const float* __restrict__ logits, const float* __restrict__ bias,
                              int* __restrict__ topk_idx, float* __restrict__ topkw) {
    int t = blockIdx.x * 256 + threadIdx.x;
    if (t >= T) return;
    float sc[NE], sfc[NE];
    for (int e = 0; e < NE; ++e) {
        float s = 1.f / (1.f + expf(-logits[(size_t)t * NE + e]));
        sc[e] = s;
        sfc[e] = s + bias[e];
    }
    float gs[NG];
    for (int g = 0; g < NG; ++g) {
        float m1 = -1e30f, m2 = -1e30f;
        for (int i = 0; i < 4; ++i) {
            float v = sfc[g * 4 + i];
            if (v > m1) { m2 = m1; m1 = v; }
            else if (v > m2) m2 = v;
        }
        gs[g] = m1 + m2;
    }
    bool gmask[NG];
    for (int g = 0; g < NG; ++g) gmask[g] = false;
    for (int r = 0; r < 4; ++r) {
        int bi = 0; float bv = -1e30f;
        for (int g = 0; g < NG; ++g)
            if (gs[g] > bv) { bv = gs[g]; bi = g; }
        gmask[bi] = true;
        gs[bi] = -1e30f;
    }
    float msfc[NE];
    for (int e = 0; e < NE; ++e) msfc[e] = gmask[e >> 2] ? sfc[e] : 0.f;
    int idx[TOPK]; float w[TOPK]; float wsum = 0.f;
    for (int r = 0; r < TOPK; ++r) {
        int bi = 0; float bv = -1e30f;
        for (int e = 0; e < NE; ++e)
            if (msfc[e] > bv) { bv = msfc[e]; bi = e; }
        idx[r] = bi;
        msfc[bi] = -1e30f;
        w[r] = sc[bi];
        wsum += w[r];
    }
    float inv = RSF / (wsum + 1e-20f);
    for (int r = 0; r < TOPK; ++r) {
        topk_idx[(size_t)t * TOPK + r] = idx[r];
        topkw[(size_t)t * TOPK + r] = w[r] * inv;
    }
}

__global__ void count_kernel(const int* __restrict__ topk_idx, int* __restrict__ counts) {
    int i = blockIdx.x * 256 + threadIdx.x;
    if (i < T * TOPK) atomicAdd(&counts[topk_idx[i]], 1);
}
__global__ void scan_kernel(const int* __restrict__ counts, int* __restrict__ offs) {
    if (threadIdx.x == 0 && blockIdx.x == 0) {
        int acc = 0;
        for (int e = 0; e < NE; ++e) { offs[e] = acc; acc += counts[e]; }
    }
}
__global__ void fill_kernel(const int* __restrict__ topk_idx,
                            const int* __restrict__ offs, int* __restrict__ fills,
                            int* __restrict__ tok_of, int* __restrict__ slot_of) {
    int i = blockIdx.x * 256 + threadIdx.x;
    if (i < T * TOPK) {
        int e = topk_idx[i];
        int p = offs[e] + atomicAdd(&fills[e], 1);
        tok_of[p] = i >> 2;
        slot_of[i] = p;
    }
}

// ---------------- dual up-proj (gate+up), bf16 MFMA, 128x64 tile, silu epilogue ------
// A: bf16 X (gathered rows if tok_of != null). B: K-major fp32 weights (cvt in staging).
// Used for both MoE experts (grid.z = NE, counts) and shared expert (grid.z = 1).
__global__ __launch_bounds__(256) void dual_up_mfma(
    const unsigned short* __restrict__ Xb, const float* __restrict__ Gw,
    const float* __restrict__ Uw, size_t wstride, const int* __restrict__ tok_of,
    const int* __restrict__ offs, const int* __restrict__ counts, int ldb,
    unsigned short* __restrict__ outb, int ldo) {
    int e = blockIdx.z;
    int cnt = counts ? counts[e] : T;
    int base = offs ? offs[e] : 0;
    int m0 = blockIdx.y * 128;
    if (m0 >= cnt) return;
    int n0 = blockIdx.x * 64;
    const float* gw = Gw + (size_t)e * wstride;
    const float* uw = Uw + (size_t)e * wstride;
    __shared__ short As[128][KP], Gs[64][KP], Us[64][KP];
    __shared__ int toks[128];
    int tid = threadIdx.x;
    if (tid < 128) {
        int m = m0 + tid;
        if (m >= cnt) m = cnt - 1;
        toks[tid] = tok_of ? tok_of[base + m] : m;
    }
    __syncthreads();
    int r = tid & 127, kq = tid >> 7;
    int nl = (tid & 15) * 4, kg = tid >> 4;  // kg 0..15 -> k rows kg*2, kg*2+1
    int wave = tid >> 6, lane = tid & 63;
    int wm = (wave >> 1) * 64, wn = (wave & 1) * 32, lr = lane & 15, lq = lane >> 4;
    f32x4 ag[4][2], au[4][2];
#pragma unroll
    for (int i = 0; i < 4; ++i)
#pragma unroll
        for (int j = 0; j < 2; ++j) {
            ag[i][j] = (f32x4){0.f, 0.f, 0.f, 0.f};
            au[i][j] = (f32x4){0.f, 0.f, 0.f, 0.f};
        }
    for (int k0 = 0; k0 < H; k0 += 32) {
        // A: straight bf16 copy (32 B per thread)
        {
            const unsigned short* src = Xb + (size_t)toks[r] * H + k0 + kq * 16;
            uint4 p0 = *(const uint4*)src;
            uint4 p1 = *(const uint4*)(src + 8);
            *(uint4*)&As[r][kq * 16] = p0;
            *(uint4*)&As[r][kq * 16 + 8] = p1;
        }
        // B: K-major -> [n][k] transpose with fp32->bf16 cvt (2x4 blocks)
        {
            const float* s = gw + (size_t)(k0 + kg * 2) * ldb + n0 + nl;
            float4 r0 = *(const float4*)s;
            float4 r1 = *(const float4*)(s + ldb);
            float a0[4] = {r0.x, r0.y, r0.z, r0.w};
            float a1[4] = {r1.x, r1.y, r1.z, r1.w};
#pragma unroll
            for (int c = 0; c < 4; ++c)
                *(unsigned*)&Gs[nl + c][kg * 2] =
                    (unsigned)f2bf(a0[c]) | ((unsigned)f2bf(a1[c]) << 16);
            s = uw + (size_t)(k0 + kg * 2) * ldb + n0 + nl;
            r0 = *(const float4*)s;
            r1 = *(const float4*)(s + ldb);
            float b0[4] = {r0.x, r0.y, r0.z, r0.w};
            float b1[4] = {r1.x, r1.y, r1.z, r1.w};
#pragma unroll
            for (int c = 0; c < 4; ++c)
                *(unsigned*)&Us[nl + c][kg * 2] =
                    (unsigned)f2bf(b0[c]) | ((unsigned)f2bf(b1[c]) << 16);
        }
        __syncthreads();
        bf16x8 a[4], g[2], u[2];
#pragma unroll
        for (int mt = 0; mt < 4; ++mt)
            a[mt] = *(const bf16x8*)&As[wm + mt * 16 + lr][lq * 8];
#pragma unroll
        for (int nt = 0; nt < 2; ++nt) {
            g[nt] = *(const bf16x8*)&Gs[wn + nt * 16 + lr][lq * 8];
            u[nt] = *(const bf16x8*)&Us[wn + nt * 16 + lr][lq * 8];
        }
#pragma unroll
        for (int mt = 0; mt < 4; ++mt)
#pragma unroll
            for (int nt = 0; nt < 2; ++nt) {
                ag[mt][nt] = MFMA16(a[mt], g[nt], ag[mt][nt]);
                au[mt][nt] = MFMA16(a[mt], u[nt], au[mt][nt]);
            }
        __syncthreads();
    }
#pragma unroll
    for (int mt = 0; mt < 4; ++mt)
#pragma unroll
        for (int nt = 0; nt < 2; ++nt)
#pragma unroll
            for (int p = 0; p < 4; ++p) {
                int m = m0 + wm + mt * 16 + lq * 4 + p;
                if (m >= cnt) continue;
                int orow = tok_of ? base + m : m;
                int col = n0 + wn + nt * 16 + lr;
                float gv = ag[mt][nt][p], uv = au[mt][nt][p];
                float sv = gv / (1.f + __expf(-gv)) * uv;
                outb[(size_t)orow * ldo + col] = f2bf(sv);
            }
}

// ---------------- down-proj, bf16 MFMA, 128x128 tile, fp32 out -----------------------
// A: bf16 (abuf slots or ashared tokens). B: K-major fp32 (cvt in staging).
__global__ __launch_bounds__(256) void down_mfma(const unsigned short* __restrict__ Ab, int lda,
                                                 int K, const float* __restrict__ Ww,
                                                 size_t wstride, int ldb,
                                                 const int* __restrict__ offs,
                                                 const int* __restrict__ counts,
                                                 float* __restrict__ Co, int ldc) {
    int e = blockIdx.z;
    int cnt = counts ? counts[e] : T;
    int base = offs ? offs[e] : 0;
    int m0 = blockIdx.y * 128;
    if (m0 >= cnt) return;
    int n0 = blockIdx.x * 128;
    const float* w = Ww + (size_t)e * wstride;
    __shared__ short As[128][KP], Bs[128][KP];
    int tid = threadIdx.x;
    int r = tid & 127, kq = tid >> 7;
    int am = m0 + r;
    if (am >= cnt) am = cnt - 1;
    const unsigned short* arow = Ab + (size_t)(base + am) * lda;
    int nl = (tid & 31) * 4, kg = tid >> 5;  // kg 0..7 -> k rows kg*4..+3
    int wave = tid >> 6, lane = tid & 63;
    int wm = (wave >> 1) * 64, wn = (wave & 1) * 64, lr = lane & 15, lq = lane >> 4;
    f32x4 acc[4][4];
#pragma unroll
    for (int i = 0; i < 4; ++i)
#pragma unroll
        for (int j = 0; j < 4; ++j) acc[i][j] = (f32x4){0.f, 0.f, 0.f, 0.f};
    for (int k0 = 0; k0 < K; k0 += 32) {
        {
            uint4 p0 = *(const uint4*)(arow + k0 + kq * 16);
            uint4 p1 = *(const uint4*)(arow + k0 + kq * 16 + 8);
            *(uint4*)&As[r][kq * 16] = p0;
            *(uint4*)&As[r][kq * 16 + 8] = p1;
        }
        {
            const float* s = w + (size_t)(k0 + kg * 4) * ldb + n0 + nl;
            float4 r0 = *(const float4*)s;
            float4 r1 = *(const float4*)(s + ldb);
            float4 r2 = *(const float4*)(s + 2 * ldb);
            float4 r3 = *(const float4*)(s + 3 * ldb);
            float a0[4] = {r0.x, r0.y, r0.z, r0.w};
            float a1[4] = {r1.x, r1.y, r1.z, r1.w};
            float a2[4] = {r2.x, r2.y, r2.z, r2.w};
            float a3[4] = {r3.x, r3.y, r3.z, r3.w};
#pragma unroll
            for (int c = 0; c < 4; ++c) {
                uint2 pk;
                pk.x = (unsigned)f2bf(a0[c]) | ((unsigned)f2bf(a1[c]) << 16);
                pk.y = (unsigned)f2bf(a2[c]) | ((unsigned)f2bf(a3[c]) << 16);
                *(uint2*)&Bs[nl + c][kg * 4] = pk;
            }
        }
        __syncthreads();
        bf16x8 a[4], b[4];
#pragma unroll
        for (int mt = 0; mt < 4; ++mt)
            a[mt] = *(const bf16x8*)&As[wm + mt * 16 + lr][lq * 8];
#pragma unroll
        for (int nt = 0; nt < 4; ++nt)
            b[nt] = *(const bf16x8*)&Bs[wn + nt * 16 + lr][lq * 8];
#pragma unroll
        for (int mt = 0; mt < 4; ++mt)
#pragma unroll
            for (int nt = 0; nt < 4; ++nt) acc[mt][nt] = MFMA16(a[mt], b[nt], acc[mt][nt]);
        __syncthreads();
    }
#pragma unroll
    for (int mt = 0; mt < 4; ++mt)
#pragma unroll
        for (int nt = 0; nt < 4; ++nt)
#pragma unroll
            for (int p = 0; p < 4; ++p) {
                int m = m0 + wm + mt * 16 + lq * 4 + p;
                if (m >= cnt) continue;
                int col = n0 + wn + nt * 16 + lr;
                Co[(size_t)(base + m) * ldc + col] = acc[mt][nt][p];
            }
}

// ---------------- final combine ----------------
__global__ void combine_kernel(const float* __restrict__ o_slot, const int* __restrict__ slot_of,
                               const float* __restrict__ topkw, const float* __restrict__ h2,
                               const float* __restrict__ sharedo, float* __restrict__ out) {
    int t = blockIdx.x;
    int d = threadIdx.x * 4;
    float4 a = *(const float4*)&h2[(size_t)t * H + d];
    float4 b = *(const float4*)&sharedo[(size_t)t * H + d];
    float4 acc = make_float4(a.x + b.x, a.y + b.y, a.z + b.z, a.w + b.w);
#pragma unroll
    for (int r = 0; r < TOPK; ++r) {
        int s = slot_of[t * TOPK + r];
        float w = topkw[t * TOPK + r];
        float4 v = *(const float4*)&o_slot[(size_t)s * H + d];
        acc.x += w * v.x; acc.y += w * v.y; acc.z += w * v.z; acc.w += w * v.w;
    }
    *(float4*)&out[(size_t)t * H + d] = acc;
}

// ---------------- launch ----------------
extern "C" void kernel_launch(void* const* d_in, const int* in_sizes, int n_in,
                              void* d_out, int out_size, void* d_ws, size_t ws_size,
                              hipStream_t stream) {
    const float* hidden = (const float*)d_in[0];
    const int* pos = (const int*)d_in[1];
    const float* ln1w = (const float*)d_in[2];
    const float* ln2w = (const float*)d_in[3];
    const float* q_w = (const float*)d_in[4];
    const float* k_w = (const float*)d_in[5];
    const float* v_w = (const float*)d_in[6];
    const float* o_w = (const float*)d_in[7];
    const float* router_w = (const float*)d_in[8];
    const float* router_b = (const float*)d_in[9];
    const float* eg_w = (const float*)d_in[10];
    const float* eu_w = (const float*)d_in[11];
    const float* ed_w = (const float*)d_in[12];
    const float* sg_w = (const float*)d_in[13];
    const float* su_w = (const float*)d_in[14];
    const float* sd_w = (const float*)d_in[15];
    float* out = (float*)d_out;

    float* f = (float*)d_ws;
    float* h_ln1 = f;   f += (size_t)T * H;
    float* qb = f;      f += (size_t)T * H;
    float* kb = f;      f += (size_t)T * NKV * HD;
    float* vb = f;      f += (size_t)T * NKV * HD;
    float* attno = f;   f += (size_t)T * H;
    float* h2 = f;      f += (size_t)T * H;
    float* h_ln2f = f;  f += (size_t)T * H;
    float* logits = f;  f += (size_t)T * NE;
    float* topkw = f;   f += (size_t)T * TOPK;
    float* o_slot = f;  f += (size_t)T * TOPK * H;
    float* sharedo = f; f += (size_t)T * H;
    unsigned short* h_ln2b = (unsigned short*)f;
    unsigned short* abuf = h_ln2b + (size_t)T * H;
    unsigned short* ashared = abuf + (size_t)T * TOPK * MI;
    int* topk_idx = (int*)(ashared + (size_t)T * SI);
    int* counts = topk_idx + T * TOPK;
    int* fills = counts + NE;
    int* offs = fills + NE;
    int* tok_of = offs + NE;
    int* slot_of = tok_of + T * TOPK;

    dim3 b256(256);

    rmsnorm_kernel<<<T, b256, 0, stream>>>(hidden, ln1w, h_ln1);
    gemm_qkv_mfma<<<dim3(16, 8), b256, 0, stream>>>(h_ln1, q_w, k_w, v_w, qb, kb, vb);
    {
        int tot = T * NH * 64 + T * NKV * 64;
        rope_kernel<<<(tot + 255) / 256, b256, 0, stream>>>(qb, kb, pos);
    }
    attn_kernel<<<dim3(NH, T / 32), b256, 0, stream>>>(qb, kb, vb, attno);
    gemm_bt_res_mfma<<<dim3(8, 8), b256, 0, stream>>>(attno, o_w, hidden, h2);
    rmsnorm_dual_kernel<<<T, b256, 0, stream>>>(h2, ln2w, h_ln2f, h_ln2b);

    gemm_small_bt<<<dim3(1, T / GT), b256, 0, stream>>>(h_ln2f, router_w, logits, T, NE, H);
    router_kernel<<<(T + 255) / 256, b256, 0, stream>>>(logits, router_b, topk_idx, topkw);
    zero_i_kernel<<<1, b256, 0, stream>>>(counts, 2 * NE);
    count_kernel<<<(T * TOPK + 255) / 256, b256, 0, stream>>>(topk_idx, counts);
    scan_kernel<<<1, 1, 0, stream>>>(counts, offs);
    fill_kernel<<<(T * TOPK + 255) / 256, b256, 0, stream>>>(topk_idx, offs, fills, tok_of, slot_of);

    // MoE experts
    dual_up_mfma<<<dim3(MI / 64, (T * TOPK) / 128, NE), b256, 0, stream>>>(
        h_ln2b, eg_w, eu_w, (size_t)H * MI, tok_of, offs, counts, MI, abuf, MI);
    down_mfma<<<dim3(H / 128, (T * TOPK) / 128, NE), b256, 0, stream>>>(
        abuf, MI, MI, ed_w, (size_t)MI * H, H, offs, counts, o_slot, H);

    // shared expert
    dual_up_mfma<<<dim3(SI / 64, T / 128, 1), b256, 0, stream>>>(
        h_ln2b, sg_w, su_w, 0, nullptr, nullptr, nullptr, SI, ashared, SI);
    down_mfma<<<dim3(H / 128, T / 128, 1), b256, 0, stream>>>(
        ashared, SI, SI, sd_w, 0, H, nullptr, nullptr, sharedo, H);

    combine_kernel<<<T, b256, 0, stream>>>(o_slot, slot_of, topkw, h2, sharedo, out);
}

// Round 4
// 899.962 us; speedup vs baseline: 3.1762x; 1.2521x over previous
//
#include <hip/hip_runtime.h>
#include <math.h>

#define T 1024
#define H 1024
#define NH 8
#define NKV 4
#define HD 128
#define NE 32
#define TOPK 4
#define NG 8
#define MI 512
#define SI 1024
#define RSF 2.5f
#define EPS 1e-6f

// small-GEMM (router) tile params
#define GT 64
#define GKT 16
#define LDP 68

// MFMA LDS tile: rows padded to 40 bf16 (80 B)
#define KP 40

typedef short bf16x8 __attribute__((ext_vector_type(8)));
typedef float f32x4 __attribute__((ext_vector_type(4)));
#define MFMA16(a, b, c) __builtin_amdgcn_mfma_f32_16x16x32_bf16((a), (b), (c), 0, 0, 0)

__device__ inline unsigned short f2bf(float x) {
    unsigned u = __float_as_uint(x);
    u += 0x7fff + ((u >> 16) & 1);  // RNE
    return (unsigned short)(u >> 16);
}
__device__ inline float bf2f(unsigned short h) { return __uint_as_float(((unsigned)h) << 16); }

union U16S {
    unsigned short s[16];
    uint4 q[2];
};

// ---------------- elementwise / norm ----------------
__global__ void rmsnorm_kernel(const float* __restrict__ x, const float* __restrict__ w,
                               float* __restrict__ out) {
    int t = blockIdx.x;
    __shared__ float red[256];
    const float* xr = x + (size_t)t * H;
    float s = 0.f;
    for (int i = threadIdx.x; i < H; i += 256) { float v = xr[i]; s += v * v; }
    red[threadIdx.x] = s;
    __syncthreads();
    for (int st = 128; st > 0; st >>= 1) {
        if (threadIdx.x < st) red[threadIdx.x] += red[threadIdx.x + st];
        __syncthreads();
    }
    float inv = rsqrtf(red[0] / (float)H + EPS);
    float* orow = out + (size_t)t * H;
    for (int i = threadIdx.x; i < H; i += 256) orow[i] = xr[i] * inv * w[i];
}

__global__ void rmsnorm_dual_kernel(const float* __restrict__ x, const float* __restrict__ w,
                                    float* __restrict__ outf, unsigned short* __restrict__ outb) {
    int t = blockIdx.x;
    __shared__ float red[256];
    const float* xr = x + (size_t)t * H;
    float s = 0.f;
    for (int i = threadIdx.x; i < H; i += 256) { float v = xr[i]; s += v * v; }
    red[threadIdx.x] = s;
    __syncthreads();
    for (int st = 128; st > 0; st >>= 1) {
        if (threadIdx.x < st) red[threadIdx.x] += red[threadIdx.x + st];
        __syncthreads();
    }
    float inv = rsqrtf(red[0] / (float)H + EPS);
    for (int i = threadIdx.x; i < H; i += 256) {
        float v = xr[i] * inv * w[i];
        outf[(size_t)t * H + i] = v;
        outb[(size_t)t * H + i] = f2bf(v);
    }
}

__global__ void zero_i_kernel(int* p, int n) {
    int i = blockIdx.x * 256 + threadIdx.x;
    if (i < n) p[i] = 0;
}

// ---------------- small tiled SGEMM (router only, fp32 exact path) ----------------
__global__ void gemm_small_bt(const float* __restrict__ A, const float* __restrict__ B,
                              float* __restrict__ C, int M, int N, int K) {
    __shared__ float As[GKT][LDP];
    __shared__ float Bs[GKT][LDP];
    int tid = threadIdx.x;
    int tx = tid & 15, ty = tid >> 4;
    int m0 = blockIdx.y * GT, n0 = blockIdx.x * GT;
    float acc[4][4] = {};
    for (int k0 = 0; k0 < K; k0 += GKT) {
        for (int mm = ty; mm < GT; mm += 16) {
            int gm = m0 + mm;
            As[tx][mm] = (gm < M) ? A[(size_t)gm * K + k0 + tx] : 0.f;
        }
        for (int nn = ty; nn < GT; nn += 16) {
            int gn = n0 + nn;
            Bs[tx][nn] = (gn < N) ? B[(size_t)gn * K + k0 + tx] : 0.f;
        }
        __syncthreads();
#pragma unroll
        for (int kk = 0; kk < GKT; ++kk) {
            float4 a4 = *(const float4*)&As[kk][ty * 4];
            float4 b4 = *(const float4*)&Bs[kk][tx * 4];
            float av[4] = {a4.x, a4.y, a4.z, a4.w};
            float bv[4] = {b4.x, b4.y, b4.z, b4.w};
#pragma unroll
            for (int i = 0; i < 4; ++i)
#pragma unroll
                for (int j = 0; j < 4; ++j) acc[i][j] += av[i] * bv[j];
        }
        __syncthreads();
    }
    for (int i = 0; i < 4; ++i) {
        int gm = m0 + ty * 4 + i;
        if (gm >= M) continue;
        for (int j = 0; j < 4; ++j) {
            int gn = n0 + tx * 4 + j;
            if (gn < N) C[(size_t)gm * N + gn] = acc[i][j];
        }
    }
}

// ---------------- compensated bf16 MFMA GEMM, BT weights (N x K), fused QKV -----------
__global__ __launch_bounds__(256) void gemm_qkv_mfma(const float* __restrict__ X,
                                                     const float* __restrict__ qw,
                                                     const float* __restrict__ kw,
                                                     const float* __restrict__ vw,
                                                     float* __restrict__ qo,
                                                     float* __restrict__ ko,
                                                     float* __restrict__ vo) {
    __shared__ short Ah[128][KP], Al[128][KP], Bh[128][KP], Bl[128][KP];
    int tid = threadIdx.x;
    int m0 = blockIdx.y * 128;
    int n0 = blockIdx.x * 128;
    const float* W;
    float* O;
    int ldo, nc0;
    if (n0 < 1024) { nc0 = n0; W = qw; O = qo; ldo = H; }
    else if (n0 < 1536) { nc0 = n0 - 1024; W = kw; O = ko; ldo = NKV * HD; }
    else { nc0 = n0 - 1536; W = vw; O = vo; ldo = NKV * HD; }
    W += (size_t)nc0 * H;
    int r = tid & 127, kq = tid >> 7;
    int wave = tid >> 6, lane = tid & 63;
    int wm = (wave >> 1) * 64, wn = (wave & 1) * 64, lr = lane & 15, lq = lane >> 4;
    f32x4 acc[4][4];
#pragma unroll
    for (int i = 0; i < 4; ++i)
#pragma unroll
        for (int j = 0; j < 4; ++j) acc[i][j] = (f32x4){0.f, 0.f, 0.f, 0.f};
    for (int k0 = 0; k0 < H; k0 += 32) {
        {
            const float* src = X + (size_t)(m0 + r) * H + k0 + kq * 16;
            U16S hi, lo;
#pragma unroll
            for (int j4 = 0; j4 < 4; ++j4) {
                float4 v = *(const float4*)(src + j4 * 4);
                float vv[4] = {v.x, v.y, v.z, v.w};
#pragma unroll
                for (int j = 0; j < 4; ++j) {
                    unsigned short h = f2bf(vv[j]);
                    hi.s[j4 * 4 + j] = h;
                    lo.s[j4 * 4 + j] = f2bf(vv[j] - bf2f(h));
                }
            }
            *(uint4*)&Ah[r][kq * 16] = hi.q[0];
            *(uint4*)&Ah[r][kq * 16 + 8] = hi.q[1];
            *(uint4*)&Al[r][kq * 16] = lo.q[0];
            *(uint4*)&Al[r][kq * 16 + 8] = lo.q[1];
        }
        {
            const float* src = W + (size_t)r * H + k0 + kq * 16;
            U16S hi, lo;
#pragma unroll
            for (int j4 = 0; j4 < 4; ++j4) {
                float4 v = *(const float4*)(src + j4 * 4);
                float vv[4] = {v.x, v.y, v.z, v.w};
#pragma unroll
                for (int j = 0; j < 4; ++j) {
                    unsigned short h = f2bf(vv[j]);
                    hi.s[j4 * 4 + j] = h;
                    lo.s[j4 * 4 + j] = f2bf(vv[j] - bf2f(h));
                }
            }
            *(uint4*)&Bh[r][kq * 16] = hi.q[0];
            *(uint4*)&Bh[r][kq * 16 + 8] = hi.q[1];
            *(uint4*)&Bl[r][kq * 16] = lo.q[0];
            *(uint4*)&Bl[r][kq * 16 + 8] = lo.q[1];
        }
        __syncthreads();
        bf16x8 ah[4], al[4], bh[4], bl[4];
#pragma unroll
        for (int mt = 0; mt < 4; ++mt) {
            ah[mt] = *(const bf16x8*)&Ah[wm + mt * 16 + lr][lq * 8];
            al[mt] = *(const bf16x8*)&Al[wm + mt * 16 + lr][lq * 8];
        }
#pragma unroll
        for (int nt = 0; nt < 4; ++nt) {
            bh[nt] = *(const bf16x8*)&Bh[wn + nt * 16 + lr][lq * 8];
            bl[nt] = *(const bf16x8*)&Bl[wn + nt * 16 + lr][lq * 8];
        }
#pragma unroll
        for (int mt = 0; mt < 4; ++mt)
#pragma unroll
            for (int nt = 0; nt < 4; ++nt) {
                acc[mt][nt] = MFMA16(ah[mt], bh[nt], acc[mt][nt]);
                acc[mt][nt] = MFMA16(ah[mt], bl[nt], acc[mt][nt]);
                acc[mt][nt] = MFMA16(al[mt], bh[nt], acc[mt][nt]);
            }
        __syncthreads();
    }
#pragma unroll
    for (int mt = 0; mt < 4; ++mt)
#pragma unroll
        for (int nt = 0; nt < 4; ++nt)
#pragma unroll
            for (int p = 0; p < 4; ++p) {
                int m = m0 + wm + mt * 16 + lq * 4 + p;
                int col = nc0 + wn + nt * 16 + lr;
                O[(size_t)m * ldo + col] = acc[mt][nt][p];
            }
}

// ---------------- compensated bf16 MFMA GEMM, single BT weight + residual add --------
__global__ __launch_bounds__(256) void gemm_bt_res_mfma(const float* __restrict__ X,
                                                        const float* __restrict__ Wm,
                                                        const float* __restrict__ res,
                                                        float* __restrict__ O) {
    __shared__ short Ah[128][KP], Al[128][KP], Bh[128][KP], Bl[128][KP];
    int tid = threadIdx.x;
    int m0 = blockIdx.y * 128;
    int n0 = blockIdx.x * 128;
    const float* W = Wm + (size_t)n0 * H;
    int r = tid & 127, kq = tid >> 7;
    int wave = tid >> 6, lane = tid & 63;
    int wm = (wave >> 1) * 64, wn = (wave & 1) * 64, lr = lane & 15, lq = lane >> 4;
    f32x4 acc[4][4];
#pragma unroll
    for (int i = 0; i < 4; ++i)
#pragma unroll
        for (int j = 0; j < 4; ++j) acc[i][j] = (f32x4){0.f, 0.f, 0.f, 0.f};
    for (int k0 = 0; k0 < H; k0 += 32) {
        {
            const float* src = X + (size_t)(m0 + r) * H + k0 + kq * 16;
            U16S hi, lo;
#pragma unroll
            for (int j4 = 0; j4 < 4; ++j4) {
                float4 v = *(const float4*)(src + j4 * 4);
                float vv[4] = {v.x, v.y, v.z, v.w};
#pragma unroll
                for (int j = 0; j < 4; ++j) {
                    unsigned short h = f2bf(vv[j]);
                    hi.s[j4 * 4 + j] = h;
                    lo.s[j4 * 4 + j] = f2bf(vv[j] - bf2f(h));
                }
            }
            *(uint4*)&Ah[r][kq * 16] = hi.q[0];
            *(uint4*)&Ah[r][kq * 16 + 8] = hi.q[1];
            *(uint4*)&Al[r][kq * 16] = lo.q[0];
            *(uint4*)&Al[r][kq * 16 + 8] = lo.q[1];
        }
        {
            const float* src = W + (size_t)r * H + k0 + kq * 16;
            U16S hi, lo;
#pragma unroll
            for (int j4 = 0; j4 < 4; ++j4) {
                float4 v = *(const float4*)(src + j4 * 4);
                float vv[4] = {v.x, v.y, v.z, v.w};
#pragma unroll
                for (int j = 0; j < 4; ++j) {
                    unsigned short h = f2bf(vv[j]);
                    hi.s[j4 * 4 + j] = h;
                    lo.s[j4 * 4 + j] = f2bf(vv[j] - bf2f(h));
                }
            }
            *(uint4*)&Bh[r][kq * 16] = hi.q[0];
            *(uint4*)&Bh[r][kq * 16 + 8] = hi.q[1];
            *(uint4*)&Bl[r][kq * 16] = lo.q[0];
            *(uint4*)&Bl[r][kq * 16 + 8] = lo.q[1];
        }
        __syncthreads();
        bf16x8 ah[4], al[4], bh[4], bl[4];
#pragma unroll
        for (int mt = 0; mt < 4; ++mt) {
            ah[mt] = *(const bf16x8*)&Ah[wm + mt * 16 + lr][lq * 8];
            al[mt] = *(const bf16x8*)&Al[wm + mt * 16 + lr][lq * 8];
        }
#pragma unroll
        for (int nt = 0; nt < 4; ++nt) {
            bh[nt] = *(const bf16x8*)&Bh[wn + nt * 16 + lr][lq * 8];
            bl[nt] = *(const bf16x8*)&Bl[wn + nt * 16 + lr][lq * 8];
        }
#pragma unroll
        for (int mt = 0; mt < 4; ++mt)
#pragma unroll
            for (int nt = 0; nt < 4; ++nt) {
                acc[mt][nt] = MFMA16(ah[mt], bh[nt], acc[mt][nt]);
                acc[mt][nt] = MFMA16(ah[mt], bl[nt], acc[mt][nt]);
                acc[mt][nt] = MFMA16(al[mt], bh[nt], acc[mt][nt]);
            }
        __syncthreads();
    }
#pragma unroll
    for (int mt = 0; mt < 4; ++mt)
#pragma unroll
        for (int nt = 0; nt < 4; ++nt)
#pragma unroll
            for (int p = 0; p < 4; ++p) {
                int m = m0 + wm + mt * 16 + lq * 4 + p;
                int col = n0 + wn + nt * 16 + lr;
                O[(size_t)m * H + col] = res[(size_t)m * H + col] + acc[mt][nt][p];
            }
}

// ---------------- rope ----------------
__global__ void rope_kernel(float* __restrict__ q, float* __restrict__ k,
                            const int* __restrict__ pos) {
    int i = blockIdx.x * 256 + threadIdx.x;
    const int totq = T * NH * 64;
    const int tot = totq + T * NKV * 64;
    if (i >= tot) return;
    float* buf;
    int t, hh, d, nh;
    if (i < totq) {
        buf = q; nh = NH;
        int r = i; d = r & 63; r >>= 6; hh = r % NH; t = r / NH;
    } else {
        buf = k; nh = NKV;
        int r = i - totq; d = r & 63; r >>= 6; hh = r % NKV; t = r / NKV;
    }
    float p = (float)pos[t];
    float inv = powf(10000.0f, -(float)d / 64.0f);
    float fr = p * inv;
    float sv, cv;
    sincosf(fr, &sv, &cv);
    size_t bi = ((size_t)t * nh + hh) * HD + d;
    float x1 = buf[bi], x2 = buf[bi + 64];
    buf[bi] = x1 * cv - x2 * sv;
    buf[bi + 64] = x2 * cv + x1 * sv;
}

// ---------------- flash attention, compensated bf16 MFMA ----------------
// grid (NH, T/64); block 256 = 4 waves; wave w owns q-rows q0+16w..+15.
// K LDS [key][d] stride 140; V LDS transposed [d][key] stride 42; P per-wave stride 34.
#define KS_LD 140
#define VS_LD 42
#define PS_LD 34
__global__ __launch_bounds__(256) void attn_mfma(const float* __restrict__ Q,
                                                 const float* __restrict__ Kb,
                                                 const float* __restrict__ Vb,
                                                 float* __restrict__ O) {
    int h = blockIdx.x;
    int qb = blockIdx.y;
    int kvh = h >> 1;  // NH/NKV = 2
    int q0 = qb * 64;
    __shared__ short Ksh[32][KS_LD], Ksl[32][KS_LD];
    __shared__ short Vsh[128][VS_LD], Vsl[128][VS_LD];
    __shared__ short Ph[4][16][PS_LD], Pl[4][16][PS_LD];
    int tid = threadIdx.x;
    int wave = tid >> 6, lane = tid & 63;
    int lr = lane & 15, lq = lane >> 4;
    const float scale = 0.08838834764831845f;  // 1/sqrt(128)

    // Q fragments (hi/lo) in registers for the whole sweep
    bf16x8 qh[4], ql[4];
    {
        const float* qrow = Q + (size_t)(q0 + wave * 16 + lr) * H + h * HD;
#pragma unroll
        for (int c = 0; c < 4; ++c) {
            float4 v0 = *(const float4*)(qrow + c * 32 + lq * 8);
            float4 v1 = *(const float4*)(qrow + c * 32 + lq * 8 + 4);
            float vv[8] = {v0.x, v0.y, v0.z, v0.w, v1.x, v1.y, v1.z, v1.w};
#pragma unroll
            for (int j = 0; j < 8; ++j) {
                unsigned short hb = f2bf(vv[j]);
                qh[c][j] = (short)hb;
                ql[c][j] = (short)f2bf(vv[j] - bf2f(hb));
            }
        }
    }
    f32x4 o[8];
#pragma unroll
    for (int nt = 0; nt < 8; ++nt) o[nt] = (f32x4){0.f, 0.f, 0.f, 0.f};
    float m_r[4] = {-1e30f, -1e30f, -1e30f, -1e30f};
    float l_r[4] = {0.f, 0.f, 0.f, 0.f};

    int ktmax = (q0 >> 5) + 2;
    int ntw = ((q0 + wave * 16 + 15) >> 5) + 1;  // wave-uniform causal tile count
    int d0 = (tid & 31) * 4, rb = tid >> 5;

    for (int kt = 0; kt < ktmax; ++kt) {
        int k0 = kt * 32;
        // ---- stage K (hi/lo), coalesced float4 reads ----
#pragma unroll
        for (int pass = 0; pass < 4; ++pass) {
            int key = rb + pass * 8;
            float4 v = *(const float4*)&Kb[(size_t)(k0 + key) * (NKV * HD) + kvh * HD + d0];
            float vv[4] = {v.x, v.y, v.z, v.w};
            uint2 hi, lo;
            unsigned short h0 = f2bf(vv[0]), h1 = f2bf(vv[1]);
            unsigned short h2b = f2bf(vv[2]), h3 = f2bf(vv[3]);
            hi.x = (unsigned)h0 | ((unsigned)h1 << 16);
            hi.y = (unsigned)h2b | ((unsigned)h3 << 16);
            lo.x = (unsigned)f2bf(vv[0] - bf2f(h0)) | ((unsigned)f2bf(vv[1] - bf2f(h1)) << 16);
            lo.y = (unsigned)f2bf(vv[2] - bf2f(h2b)) | ((unsigned)f2bf(vv[3] - bf2f(h3)) << 16);
            *(uint2*)&Ksh[key][d0] = hi;
            *(uint2*)&Ksl[key][d0] = lo;
        }
        // ---- stage V transposed (hi/lo) ----
#pragma unroll
        for (int pass = 0; pass < 4; ++pass) {
            int key = rb + pass * 8;
            float4 v = *(const float4*)&Vb[(size_t)(k0 + key) * (NKV * HD) + kvh * HD + d0];
            float vv[4] = {v.x, v.y, v.z, v.w};
#pragma unroll
            for (int j = 0; j < 4; ++j) {
                unsigned short hb = f2bf(vv[j]);
                Vsh[d0 + j][key] = (short)hb;
                Vsl[d0 + j][key] = (short)f2bf(vv[j] - bf2f(hb));
            }
        }
        __syncthreads();
        if (kt < ntw) {
            // ---- QK^T: 2 col-tiles, compensated ----
            f32x4 s[2];
            s[0] = (f32x4){0.f, 0.f, 0.f, 0.f};
            s[1] = (f32x4){0.f, 0.f, 0.f, 0.f};
#pragma unroll
            for (int nt = 0; nt < 2; ++nt)
#pragma unroll
                for (int c = 0; c < 4; ++c) {
                    bf16x8 kh = *(const bf16x8*)&Ksh[nt * 16 + lr][c * 32 + lq * 8];
                    bf16x8 kl = *(const bf16x8*)&Ksl[nt * 16 + lr][c * 32 + lq * 8];
                    s[nt] = MFMA16(qh[c], kh, s[nt]);
                    s[nt] = MFMA16(ql[c], kh, s[nt]);
                    s[nt] = MFMA16(qh[c], kl, s[nt]);
                }
            // ---- scale + causal mask ----
            int gr_base = q0 + wave * 16 + lq * 4;
#pragma unroll
            for (int nt = 0; nt < 2; ++nt) {
                int gc = k0 + nt * 16 + lr;
#pragma unroll
                for (int p = 0; p < 4; ++p) {
                    float sv = s[nt][p] * scale;
                    if (gc > gr_base + p) sv = -1e30f;
                    s[nt][p] = sv;
                }
            }
            // ---- online softmax, per-row (p) across 16 lr lanes ----
            float alpha[4];
#pragma unroll
            for (int p = 0; p < 4; ++p) {
                float mx = fmaxf(s[0][p], s[1][p]);
#pragma unroll
                for (int off = 1; off < 16; off <<= 1) mx = fmaxf(mx, __shfl_xor(mx, off));
                float mn = fmaxf(m_r[p], mx);
                alpha[p] = __expf(m_r[p] - mn);
                float p0 = __expf(s[0][p] - mn);
                float p1 = __expf(s[1][p] - mn);
                float ps = p0 + p1;
#pragma unroll
                for (int off = 1; off < 16; off <<= 1) ps += __shfl_xor(ps, off);
                l_r[p] = l_r[p] * alpha[p] + ps;
                m_r[p] = mn;
                int r = lq * 4 + p;
                unsigned short h0 = f2bf(p0);
                Ph[wave][r][lr] = (short)h0;
                Pl[wave][r][lr] = (short)f2bf(p0 - bf2f(h0));
                unsigned short h1 = f2bf(p1);
                Ph[wave][r][lr + 16] = (short)h1;
                Pl[wave][r][lr + 16] = (short)f2bf(p1 - bf2f(h1));
            }
            // ---- P·V: rescale O, then compensated MFMA ----
            bf16x8 pah = *(const bf16x8*)&Ph[wave][lr][lq * 8];
            bf16x8 pal = *(const bf16x8*)&Pl[wave][lr][lq * 8];
#pragma unroll
            for (int nt = 0; nt < 8; ++nt) {
#pragma unroll
                for (int p = 0; p < 4; ++p) o[nt][p] *= alpha[p];
                bf16x8 vh = *(const bf16x8*)&Vsh[nt * 16 + lr][lq * 8];
                bf16x8 vl = *(const bf16x8*)&Vsl[nt * 16 + lr][lq * 8];
                o[nt] = MFMA16(pah, vh, o[nt]);
                o[nt] = MFMA16(pal, vh, o[nt]);
                o[nt] = MFMA16(pah, vl, o[nt]);
            }
        }
        __syncthreads();
    }
    float linv[4];
#pragma unroll
    for (int p = 0; p < 4; ++p) linv[p] = 1.f / l_r[p];
#pragma unroll
    for (int nt = 0; nt < 8; ++nt)
#pragma unroll
        for (int p = 0; p < 4; ++p) {
            int row = q0 + wave * 16 + lq * 4 + p;
            O[(size_t)row * H + h * HD + nt * 16 + lr] = o[nt][p] * linv[p];
        }
}

// ---------------- router ----------------
__global__ void router_kernel(const float* __restrict__ logits, const float* __restrict__ bias,
                              int* __restrict__ topk_idx, float* __restrict__ topkw) {
    int t = blockIdx.x * 256 + threadIdx.x;
    if (t >= T) return;
    float sc[NE], sfc[NE];
    for (int e = 0; e < NE; ++e) {
        float s = 1.f / (1.f + expf(-logits[(size_t)t * NE + e]));
        sc[e] = s;
        sfc[e] = s + bias[e];
    }
    float gs[NG];
    for (int g = 0; g < NG; ++g) {
        float m1 = -1e30f, m2 = -1e30f;
        for (int i = 0; i < 4; ++i) {
            float v = sfc[g * 4 + i];
            if (v > m1) { m2 = m1; m1 = v; }
            else if (v > m2) m2 = v;
        }
        gs[g] = m1 + m2;
    }
    bool gmask[NG];
    for (int g = 0; g < NG; ++g) gmask[g] = false;
    for (int r = 0; r < 4; ++r) {
        int bi = 0; float bv = -1e30f;
        for (int g = 0; g < NG; ++g)
            if (gs[g] > bv) { bv = gs[g]; bi = g; }
        gmask[bi] = true;
        gs[bi] = -1e30f;
    }
    float msfc[NE];
    for (int e = 0; e < NE; ++e) msfc[e] = gmask[e >> 2] ? sfc[e] : 0.f;
    int idx[TOPK]; float w[TOPK]; float wsum = 0.f;
    for (int r = 0; r < TOPK; ++r) {
        int bi = 0; float bv = -1e30f;
        for (int e = 0; e < NE; ++e)
            if (msfc[e] > bv) { bv = msfc[e]; bi = e; }
        idx[r] = bi;
        msfc[bi] = -1e30f;
        w[r] = sc[bi];
        wsum += w[r];
    }
    float inv = RSF / (wsum + 1e-20f);
    for (int r = 0; r < TOPK; ++r) {
        topk_idx[(size_t)t * TOPK + r] = idx[r];
        topkw[(size_t)t * TOPK + r] = w[r] * inv;
    }
}

__global__ void count_kernel(const int* __restrict__ topk_idx, int* __restrict__ counts) {
    int i = blockIdx.x * 256 + threadIdx.x;
    if (i < T * TOPK) atomicAdd(&counts[topk_idx[i]], 1);
}
__global__ void scan_kernel(const int* __restrict__ counts, int* __restrict__ offs) {
    if (threadIdx.x == 0 && blockIdx.x == 0) {
        int acc = 0;
        for (int e = 0; e < NE; ++e) { offs[e] = acc; acc += counts[e]; }
    }
}
__global__ void fill_kernel(const int* __restrict__ topk_idx,
                            const int* __restrict__ offs, int* __restrict__ fills,
                            int* __restrict__ tok_of, int* __restrict__ slot_of) {
    int i = blockIdx.x * 256 + threadIdx.x;
    if (i < T * TOPK) {
        int e = topk_idx[i];
        int p = offs[e] + atomicAdd(&fills[e], 1);
        tok_of[p] = i >> 2;
        slot_of[i] = p;
    }
}

// ---------------- dual up-proj (gate+up), bf16 MFMA, 128x64 tile, silu epilogue ------
__global__ __launch_bounds__(256) void dual_up_mfma(
    const unsigned short* __restrict__ Xb, const float* __restrict__ Gw,
    const float* __restrict__ Uw, size_t wstride, const int* __restrict__ tok_of,
    const int* __restrict__ offs, const int* __restrict__ counts, int ldb,
    unsigned short* __restrict__ outb, int ldo) {
    int e = blockIdx.z;
    int cnt = counts ? counts[e] : T;
    int base = offs ? offs[e] : 0;
    int m0 = blockIdx.y * 128;
    if (m0 >= cnt) return;
    int n0 = blockIdx.x * 64;
    const float* gw = Gw + (size_t)e * wstride;
    const float* uw = Uw + (size_t)e * wstride;
    __shared__ short As[128][KP], Gs[64][KP], Us[64][KP];
    __shared__ int toks[128];
    int tid = threadIdx.x;
    if (tid < 128) {
        int m = m0 + tid;
        if (m >= cnt) m = cnt - 1;
        toks[tid] = tok_of ? tok_of[base + m] : m;
    }
    __syncthreads();
    int r = tid & 127, kq = tid >> 7;
    int nl = (tid & 15) * 4, kg = tid >> 4;
    int wave = tid >> 6, lane = tid & 63;
    int wm = (wave >> 1) * 64, wn = (wave & 1) * 32, lr = lane & 15, lq = lane >> 4;
    f32x4 ag[4][2], au[4][2];
#pragma unroll
    for (int i = 0; i < 4; ++i)
#pragma unroll
        for (int j = 0; j < 2; ++j) {
            ag[i][j] = (f32x4){0.f, 0.f, 0.f, 0.f};
            au[i][j] = (f32x4){0.f, 0.f, 0.f, 0.f};
        }
    for (int k0 = 0; k0 < H; k0 += 32) {
        {
            const unsigned short* src = Xb + (size_t)toks[r] * H + k0 + kq * 16;
            uint4 p0 = *(const uint4*)src;
            uint4 p1 = *(const uint4*)(src + 8);
            *(uint4*)&As[r][kq * 16] = p0;
            *(uint4*)&As[r][kq * 16 + 8] = p1;
        }
        {
            const float* s = gw + (size_t)(k0 + kg * 2) * ldb + n0 + nl;
            float4 r0 = *(const float4*)s;
            float4 r1 = *(const float4*)(s + ldb);
            float a0[4] = {r0.x, r0.y, r0.z, r0.w};
            float a1[4] = {r1.x, r1.y, r1.z, r1.w};
#pragma unroll
            for (int c = 0; c < 4; ++c)
                *(unsigned*)&Gs[nl + c][kg * 2] =
                    (unsigned)f2bf(a0[c]) | ((unsigned)f2bf(a1[c]) << 16);
            s = uw + (size_t)(k0 + kg * 2) * ldb + n0 + nl;
            r0 = *(const float4*)s;
            r1 = *(const float4*)(s + ldb);
            float b0[4] = {r0.x, r0.y, r0.z, r0.w};
            float b1[4] = {r1.x, r1.y, r1.z, r1.w};
#pragma unroll
            for (int c = 0; c < 4; ++c)
                *(unsigned*)&Us[nl + c][kg * 2] =
                    (unsigned)f2bf(b0[c]) | ((unsigned)f2bf(b1[c]) << 16);
        }
        __syncthreads();
        bf16x8 a[4], g[2], u[2];
#pragma unroll
        for (int mt = 0; mt < 4; ++mt)
            a[mt] = *(const bf16x8*)&As[wm + mt * 16 + lr][lq * 8];
#pragma unroll
        for (int nt = 0; nt < 2; ++nt) {
            g[nt] = *(const bf16x8*)&Gs[wn + nt * 16 + lr][lq * 8];
            u[nt] = *(const bf16x8*)&Us[wn + nt * 16 + lr][lq * 8];
        }
#pragma unroll
        for (int mt = 0; mt < 4; ++mt)
#pragma unroll
            for (int nt = 0; nt < 2; ++nt) {
                ag[mt][nt] = MFMA16(a[mt], g[nt], ag[mt][nt]);
                au[mt][nt] = MFMA16(a[mt], u[nt], au[mt][nt]);
            }
        __syncthreads();
    }
#pragma unroll
    for (int mt = 0; mt < 4; ++mt)
#pragma unroll
        for (int nt = 0; nt < 2; ++nt)
#pragma unroll
            for (int p = 0; p < 4; ++p) {
                int m = m0 + wm + mt * 16 + lq * 4 + p;
                if (m >= cnt) continue;
                int orow = tok_of ? base + m : m;
                int col = n0 + wn + nt * 16 + lr;
                float gv = ag[mt][nt][p], uv = au[mt][nt][p];
                float sv = gv / (1.f + __expf(-gv)) * uv;
                outb[(size_t)orow * ldo + col] = f2bf(sv);
            }
}

// ---------------- down-proj, bf16 MFMA, 128x128 tile, fp32 out -----------------------
__global__ __launch_bounds__(256) void down_mfma(const unsigned short* __restrict__ Ab, int lda,
                                                 int K, const float* __restrict__ Ww,
                                                 size_t wstride, int ldb,
                                                 const int* __restrict__ offs,
                                                 const int* __restrict__ counts,
                                                 float* __restrict__ Co, int ldc) {
    int e = blockIdx.z;
    int cnt = counts ? counts[e] : T;
    int base = offs ? offs[e] : 0;
    int m0 = blockIdx.y * 128;
    if (m0 >= cnt) return;
    int n0 = blockIdx.x * 128;
    const float* w = Ww + (size_t)e * wstride;
    __shared__ short As[128][KP], Bs[128][KP];
    int tid = threadIdx.x;
    int r = tid & 127, kq = tid >> 7;
    int am = m0 + r;
    if (am >= cnt) am = cnt - 1;
    const unsigned short* arow = Ab + (size_t)(base + am) * lda;
    int nl = (tid & 31) * 4, kg = tid >> 5;
    int wave = tid >> 6, lane = tid & 63;
    int wm = (wave >> 1) * 64, wn = (wave & 1) * 64, lr = lane & 15, lq = lane >> 4;
    f32x4 acc[4][4];
#pragma unroll
    for (int i = 0; i < 4; ++i)
#pragma unroll
        for (int j = 0; j < 4; ++j) acc[i][j] = (f32x4){0.f, 0.f, 0.f, 0.f};
    for (int k0 = 0; k0 < K; k0 += 32) {
        {
            uint4 p0 = *(const uint4*)(arow + k0 + kq * 16);
            uint4 p1 = *(const uint4*)(arow + k0 + kq * 16 + 8);
            *(uint4*)&As[r][kq * 16] = p0;
            *(uint4*)&As[r][kq * 16 + 8] = p1;
        }
        {
            const float* s = w + (size_t)(k0 + kg * 4) * ldb + n0 + nl;
            float4 r0 = *(const float4*)s;
            float4 r1 = *(const float4*)(s + ldb);
            float4 r2 = *(const float4*)(s + 2 * ldb);
            float4 r3 = *(const float4*)(s + 3 * ldb);
            float a0[4] = {r0.x, r0.y, r0.z, r0.w};
            float a1[4] = {r1.x, r1.y, r1.z, r1.w};
            float a2[4] = {r2.x, r2.y, r2.z, r2.w};
            float a3[4] = {r3.x, r3.y, r3.z, r3.w};
#pragma unroll
            for (int c = 0; c < 4; ++c) {
                uint2 pk;
                pk.x = (unsigned)f2bf(a0[c]) | ((unsigned)f2bf(a1[c]) << 16);
                pk.y = (unsigned)f2bf(a2[c]) | ((unsigned)f2bf(a3[c]) << 16);
                *(uint2*)&Bs[nl + c][kg * 4] = pk;
            }
        }
        __syncthreads();
        bf16x8 a[4], b[4];
#pragma unroll
        for (int mt = 0; mt < 4; ++mt)
            a[mt] = *(const bf16x8*)&As[wm + mt * 16 + lr][lq * 8];
#pragma unroll
        for (int nt = 0; nt < 4; ++nt)
            b[nt] = *(const bf16x8*)&Bs[wn + nt * 16 + lr][lq * 8];
#pragma unroll
        for (int mt = 0; mt < 4; ++mt)
#pragma unroll
            for (int nt = 0; nt < 4; ++nt) acc[mt][nt] = MFMA16(a[mt], b[nt], acc[mt][nt]);
        __syncthreads();
    }
#pragma unroll
    for (int mt = 0; mt < 4; ++mt)
#pragma unroll
        for (int nt = 0; nt < 4; ++nt)
#pragma unroll
            for (int p = 0; p < 4; ++p) {
                int m = m0 + wm + mt * 16 + lq * 4 + p;
                if (m >= cnt) continue;
                int col = n0 + wn + nt * 16 + lr;
                Co[(size_t)(base + m) * ldc + col] = acc[mt][nt][p];
            }
}

// ---------------- final combine ----------------
__global__ void combine_kernel(const float* __restrict__ o_slot, const int* __restrict__ slot_of,
                               const float* __restrict__ topkw, const float* __restrict__ h2,
                               const float* __restrict__ sharedo, float* __restrict__ out) {
    int t = blockIdx.x;
    int d = threadIdx.x * 4;
    float4 a = *(const float4*)&h2[(size_t)t * H + d];
    float4 b = *(const float4*)&sharedo[(size_t)t * H + d];
    float4 acc = make_float4(a.x + b.x, a.y + b.y, a.z + b.z, a.w + b.w);
#pragma unroll
    for (int r = 0; r < TOPK; ++r) {
        int s = slot_of[t * TOPK + r];
        float w = topkw[t * TOPK + r];
        float4 v = *(const float4*)&o_slot[(size_t)s * H + d];
        acc.x += w * v.x; acc.y += w * v.y; acc.z += w * v.z; acc.w += w * v.w;
    }
    *(float4*)&out[(size_t)t * H + d] = acc;
}

// ---------------- launch ----------------
extern "C" void kernel_launch(void* const* d_in, const int* in_sizes, int n_in,
                              void* d_out, int out_size, void* d_ws, size_t ws_size,
                              hipStream_t stream) {
    const float* hidden = (const float*)d_in[0];
    const int* pos = (const int*)d_in[1];
    const float* ln1w = (const float*)d_in[2];
    const float* ln2w = (const float*)d_in[3];
    const float* q_w = (const float*)d_in[4];
    const float* k_w = (const float*)d_in[5];
    const float* v_w = (const float*)d_in[6];
    const float* o_w = (const float*)d_in[7];
    const float* router_w = (const float*)d_in[8];
    const float* router_b = (const float*)d_in[9];
    const float* eg_w = (const float*)d_in[10];
    const float* eu_w = (const float*)d_in[11];
    const float* ed_w = (const float*)d_in[12];
    const float* sg_w = (const float*)d_in[13];
    const float* su_w = (const float*)d_in[14];
    const float* sd_w = (const float*)d_in[15];
    float* out = (float*)d_out;

    float* f = (float*)d_ws;
    float* h_ln1 = f;   f += (size_t)T * H;
    float* qb = f;      f += (size_t)T * H;
    float* kb = f;      f += (size_t)T * NKV * HD;
    float* vb = f;      f += (size_t)T * NKV * HD;
    float* attno = f;   f += (size_t)T * H;
    float* h2 = f;      f += (size_t)T * H;
    float* h_ln2f = f;  f += (size_t)T * H;
    float* logits = f;  f += (size_t)T * NE;
    float* topkw = f;   f += (size_t)T * TOPK;
    float* o_slot = f;  f += (size_t)T * TOPK * H;
    float* sharedo = f; f += (size_t)T * H;
    unsigned short* h_ln2b = (unsigned short*)f;
    unsigned short* abuf = h_ln2b + (size_t)T * H;
    unsigned short* ashared = abuf + (size_t)T * TOPK * MI;
    int* topk_idx = (int*)(ashared + (size_t)T * SI);
    int* counts = topk_idx + T * TOPK;
    int* fills = counts + NE;
    int* offs = fills + NE;
    int* tok_of = offs + NE;
    int* slot_of = tok_of + T * TOPK;

    dim3 b256(256);

    rmsnorm_kernel<<<T, b256, 0, stream>>>(hidden, ln1w, h_ln1);
    gemm_qkv_mfma<<<dim3(16, 8), b256, 0, stream>>>(h_ln1, q_w, k_w, v_w, qb, kb, vb);
    {
        int tot = T * NH * 64 + T * NKV * 64;
        rope_kernel<<<(tot + 255) / 256, b256, 0, stream>>>(qb, kb, pos);
    }
    attn_mfma<<<dim3(NH, T / 64), b256, 0, stream>>>(qb, kb, vb, attno);
    gemm_bt_res_mfma<<<dim3(8, 8), b256, 0, stream>>>(attno, o_w, hidden, h2);
    rmsnorm_dual_kernel<<<T, b256, 0, stream>>>(h2, ln2w, h_ln2f, h_ln2b);

    gemm_small_bt<<<dim3(1, T / GT), b256, 0, stream>>>(h_ln2f, router_w, logits, T, NE, H);
    router_kernel<<<(T + 255) / 256, b256, 0, stream>>>(logits, router_b, topk_idx, topkw);
    zero_i_kernel<<<1, b256, 0, stream>>>(counts, 2 * NE);
    count_kernel<<<(T * TOPK + 255) / 256, b256, 0, stream>>>(topk_idx, counts);
    scan_kernel<<<1, 1, 0, stream>>>(counts, offs);
    fill_kernel<<<(T * TOPK + 255) / 256, b256, 0, stream>>>(topk_idx, offs, fills, tok_of, slot_of);

    dual_up_mfma<<<dim3(MI / 64, (T * TOPK) / 128, NE), b256, 0, stream>>>(
        h_ln2b, eg_w, eu_w, (size_t)H * MI, tok_of, offs, counts, MI, abuf, MI);
    down_mfma<<<dim3(H / 128, (T * TOPK) / 128, NE), b256, 0, stream>>>(
        abuf, MI, MI, ed_w, (size_t)MI * H, H, offs, counts, o_slot, H);

    dual_up_mfma<<<dim3(SI / 64, T / 128, 1), b256, 0, stream>>>(
        h_ln2b, sg_w, su_w, 0, nullptr, nullptr, nullptr, SI, ashared, SI);
    down_mfma<<<dim3(H / 128, T / 128, 1), b256, 0, stream>>>(
        ashared, SI, SI, sd_w, 0, H, nullptr, nullptr, sharedo, H);

    combine_kernel<<<T, b256, 0, stream>>>(o_slot, slot_of, topkw, h2, sharedo, out);
}

// Round 5
// 854.497 us; speedup vs baseline: 3.3452x; 1.0532x over previous
//
#include <hip/hip_runtime.h>
#include <math.h>

#define T 1024
#define H 1024
#define NH 8
#define NKV 4
#define HD 128
#define NE 32
#define TOPK 4
#define NG 8
#define MI 512
#define SI 1024
#define RSF 2.5f
#define EPS 1e-6f

// small-GEMM (router) tile params
#define GT 64
#define GKT 16
#define LDP 68

// MFMA LDS tile padding for the VGPR-staged (compensated) kernels
#define KP 40

typedef short bf16x8 __attribute__((ext_vector_type(8)));
typedef float f32x4 __attribute__((ext_vector_type(4)));
#define MFMA16(a, b, c) __builtin_amdgcn_mfma_f32_16x16x32_bf16((a), (b), (c), 0, 0, 0)

__device__ inline unsigned short f2bf(float x) {
    unsigned u = __float_as_uint(x);
    u += 0x7fff + ((u >> 16) & 1);  // RNE
    return (unsigned short)(u >> 16);
}
__device__ inline float bf2f(unsigned short h) { return __uint_as_float(((unsigned)h) << 16); }

union U16S {
    unsigned short s[16];
    uint4 q[2];
};

// async global -> LDS, 16 B per lane; LDS dest must be base + lane*16
__device__ __forceinline__ void gl16(const void* g, void* l) {
    __builtin_amdgcn_global_load_lds((const __attribute__((address_space(1))) unsigned int*)g,
                                     (__attribute__((address_space(3))) unsigned int*)l, 16, 0, 0);
}

// ---------------- elementwise / norm ----------------
__global__ void rmsnorm_kernel(const float* __restrict__ x, const float* __restrict__ w,
                               float* __restrict__ out) {
    int t = blockIdx.x;
    __shared__ float red[256];
    const float* xr = x + (size_t)t * H;
    float s = 0.f;
    for (int i = threadIdx.x; i < H; i += 256) { float v = xr[i]; s += v * v; }
    red[threadIdx.x] = s;
    __syncthreads();
    for (int st = 128; st > 0; st >>= 1) {
        if (threadIdx.x < st) red[threadIdx.x] += red[threadIdx.x + st];
        __syncthreads();
    }
    float inv = rsqrtf(red[0] / (float)H + EPS);
    float* orow = out + (size_t)t * H;
    for (int i = threadIdx.x; i < H; i += 256) orow[i] = xr[i] * inv * w[i];
}

__global__ void rmsnorm_dual_kernel(const float* __restrict__ x, const float* __restrict__ w,
                                    float* __restrict__ outf, unsigned short* __restrict__ outb) {
    int t = blockIdx.x;
    __shared__ float red[256];
    const float* xr = x + (size_t)t * H;
    float s = 0.f;
    for (int i = threadIdx.x; i < H; i += 256) { float v = xr[i]; s += v * v; }
    red[threadIdx.x] = s;
    __syncthreads();
    for (int st = 128; st > 0; st >>= 1) {
        if (threadIdx.x < st) red[threadIdx.x] += red[threadIdx.x + st];
        __syncthreads();
    }
    float inv = rsqrtf(red[0] / (float)H + EPS);
    for (int i = threadIdx.x; i < H; i += 256) {
        float v = xr[i] * inv * w[i];
        outf[(size_t)t * H + i] = v;
        outb[(size_t)t * H + i] = f2bf(v);
    }
}

__global__ void zero_i_kernel(int* p, int n) {
    int i = blockIdx.x * 256 + threadIdx.x;
    if (i < n) p[i] = 0;
}

// ---------------- transpose + fp32->bf16: W (K x N) -> Wt (N x K) ----------------
__global__ __launch_bounds__(256) void transpose_cvt(const float* __restrict__ W,
                                                     unsigned short* __restrict__ Wt, int K,
                                                     int N, int eoff) {
    int zl = blockIdx.z;
    const float* src = W + (size_t)(eoff + zl) * K * N;
    unsigned short* dst = Wt + (size_t)zl * K * N;
    int k0 = blockIdx.y * 64, n0 = blockIdx.x * 64;
    __shared__ unsigned short Ls[64][70];
    int tid = threadIdx.x;
    int nn = (tid & 15) * 4, kr = tid >> 4;
#pragma unroll
    for (int p = 0; p < 4; ++p) {
        int k = kr + p * 16;
        float4 v = *(const float4*)&src[(size_t)(k0 + k) * N + n0 + nn];
        Ls[k][nn] = f2bf(v.x);
        Ls[k][nn + 1] = f2bf(v.y);
        Ls[k][nn + 2] = f2bf(v.z);
        Ls[k][nn + 3] = f2bf(v.w);
    }
    __syncthreads();
    int n = tid >> 2, kq = (tid & 3) * 16;
    U16S o;
#pragma unroll
    for (int j = 0; j < 16; ++j) o.s[j] = Ls[kq + j][n];
    unsigned short* drow = dst + (size_t)(n0 + n) * K + k0 + kq;
    *(uint4*)drow = o.q[0];
    *(uint4*)(drow + 8) = o.q[1];
}

// ---------------- small tiled SGEMM (router only, fp32 exact path) ----------------
__global__ void gemm_small_bt(const float* __restrict__ A, const float* __restrict__ B,
                              float* __restrict__ C, int M, int N, int K) {
    __shared__ float As[GKT][LDP];
    __shared__ float Bs[GKT][LDP];
    int tid = threadIdx.x;
    int tx = tid & 15, ty = tid >> 4;
    int m0 = blockIdx.y * GT, n0 = blockIdx.x * GT;
    float acc[4][4] = {};
    for (int k0 = 0; k0 < K; k0 += GKT) {
        for (int mm = ty; mm < GT; mm += 16) {
            int gm = m0 + mm;
            As[tx][mm] = (gm < M) ? A[(size_t)gm * K + k0 + tx] : 0.f;
        }
        for (int nn = ty; nn < GT; nn += 16) {
            int gn = n0 + nn;
            Bs[tx][nn] = (gn < N) ? B[(size_t)gn * K + k0 + tx] : 0.f;
        }
        __syncthreads();
#pragma unroll
        for (int kk = 0; kk < GKT; ++kk) {
            float4 a4 = *(const float4*)&As[kk][ty * 4];
            float4 b4 = *(const float4*)&Bs[kk][tx * 4];
            float av[4] = {a4.x, a4.y, a4.z, a4.w};
            float bv[4] = {b4.x, b4.y, b4.z, b4.w};
#pragma unroll
            for (int i = 0; i < 4; ++i)
#pragma unroll
                for (int j = 0; j < 4; ++j) acc[i][j] += av[i] * bv[j];
        }
        __syncthreads();
    }
    for (int i = 0; i < 4; ++i) {
        int gm = m0 + ty * 4 + i;
        if (gm >= M) continue;
        for (int j = 0; j < 4; ++j) {
            int gn = n0 + tx * 4 + j;
            if (gn < N) C[(size_t)gm * N + gn] = acc[i][j];
        }
    }
}

// ---------------- compensated bf16 MFMA GEMM, BT weights (N x K), fused QKV -----------
__global__ __launch_bounds__(256) void gemm_qkv_mfma(const float* __restrict__ X,
                                                     const float* __restrict__ qw,
                                                     const float* __restrict__ kw,
                                                     const float* __restrict__ vw,
                                                     float* __restrict__ qo,
                                                     float* __restrict__ ko,
                                                     float* __restrict__ vo) {
    __shared__ short Ah[128][KP], Al[128][KP], Bh[128][KP], Bl[128][KP];
    int tid = threadIdx.x;
    int m0 = blockIdx.y * 128;
    int n0 = blockIdx.x * 128;
    const float* W;
    float* O;
    int ldo, nc0;
    if (n0 < 1024) { nc0 = n0; W = qw; O = qo; ldo = H; }
    else if (n0 < 1536) { nc0 = n0 - 1024; W = kw; O = ko; ldo = NKV * HD; }
    else { nc0 = n0 - 1536; W = vw; O = vo; ldo = NKV * HD; }
    W += (size_t)nc0 * H;
    int r = tid & 127, kq = tid >> 7;
    int wave = tid >> 6, lane = tid & 63;
    int wm = (wave >> 1) * 64, wn = (wave & 1) * 64, lr = lane & 15, lq = lane >> 4;
    f32x4 acc[4][4];
#pragma unroll
    for (int i = 0; i < 4; ++i)
#pragma unroll
        for (int j = 0; j < 4; ++j) acc[i][j] = (f32x4){0.f, 0.f, 0.f, 0.f};
    for (int k0 = 0; k0 < H; k0 += 32) {
        {
            const float* src = X + (size_t)(m0 + r) * H + k0 + kq * 16;
            U16S hi, lo;
#pragma unroll
            for (int j4 = 0; j4 < 4; ++j4) {
                float4 v = *(const float4*)(src + j4 * 4);
                float vv[4] = {v.x, v.y, v.z, v.w};
#pragma unroll
                for (int j = 0; j < 4; ++j) {
                    unsigned short h = f2bf(vv[j]);
                    hi.s[j4 * 4 + j] = h;
                    lo.s[j4 * 4 + j] = f2bf(vv[j] - bf2f(h));
                }
            }
            *(uint4*)&Ah[r][kq * 16] = hi.q[0];
            *(uint4*)&Ah[r][kq * 16 + 8] = hi.q[1];
            *(uint4*)&Al[r][kq * 16] = lo.q[0];
            *(uint4*)&Al[r][kq * 16 + 8] = lo.q[1];
        }
        {
            const float* src = W + (size_t)r * H + k0 + kq * 16;
            U16S hi, lo;
#pragma unroll
            for (int j4 = 0; j4 < 4; ++j4) {
                float4 v = *(const float4*)(src + j4 * 4);
                float vv[4] = {v.x, v.y, v.z, v.w};
#pragma unroll
                for (int j = 0; j < 4; ++j) {
                    unsigned short h = f2bf(vv[j]);
                    hi.s[j4 * 4 + j] = h;
                    lo.s[j4 * 4 + j] = f2bf(vv[j] - bf2f(h));
                }
            }
            *(uint4*)&Bh[r][kq * 16] = hi.q[0];
            *(uint4*)&Bh[r][kq * 16 + 8] = hi.q[1];
            *(uint4*)&Bl[r][kq * 16] = lo.q[0];
            *(uint4*)&Bl[r][kq * 16 + 8] = lo.q[1];
        }
        __syncthreads();
        bf16x8 ah[4], al[4], bh[4], bl[4];
#pragma unroll
        for (int mt = 0; mt < 4; ++mt) {
            ah[mt] = *(const bf16x8*)&Ah[wm + mt * 16 + lr][lq * 8];
            al[mt] = *(const bf16x8*)&Al[wm + mt * 16 + lr][lq * 8];
        }
#pragma unroll
        for (int nt = 0; nt < 4; ++nt) {
            bh[nt] = *(const bf16x8*)&Bh[wn + nt * 16 + lr][lq * 8];
            bl[nt] = *(const bf16x8*)&Bl[wn + nt * 16 + lr][lq * 8];
        }
#pragma unroll
        for (int mt = 0; mt < 4; ++mt)
#pragma unroll
            for (int nt = 0; nt < 4; ++nt) {
                acc[mt][nt] = MFMA16(ah[mt], bh[nt], acc[mt][nt]);
                acc[mt][nt] = MFMA16(ah[mt], bl[nt], acc[mt][nt]);
                acc[mt][nt] = MFMA16(al[mt], bh[nt], acc[mt][nt]);
            }
        __syncthreads();
    }
#pragma unroll
    for (int mt = 0; mt < 4; ++mt)
#pragma unroll
        for (int nt = 0; nt < 4; ++nt)
#pragma unroll
            for (int p = 0; p < 4; ++p) {
                int m = m0 + wm + mt * 16 + lq * 4 + p;
                int col = nc0 + wn + nt * 16 + lr;
                O[(size_t)m * ldo + col] = acc[mt][nt][p];
            }
}

// ---------------- compensated bf16 MFMA GEMM, single BT weight + residual add --------
__global__ __launch_bounds__(256) void gemm_bt_res_mfma(const float* __restrict__ X,
                                                        const float* __restrict__ Wm,
                                                        const float* __restrict__ res,
                                                        float* __restrict__ O) {
    __shared__ short Ah[128][KP], Al[128][KP], Bh[128][KP], Bl[128][KP];
    int tid = threadIdx.x;
    int m0 = blockIdx.y * 128;
    int n0 = blockIdx.x * 128;
    const float* W = Wm + (size_t)n0 * H;
    int r = tid & 127, kq = tid >> 7;
    int wave = tid >> 6, lane = tid & 63;
    int wm = (wave >> 1) * 64, wn = (wave & 1) * 64, lr = lane & 15, lq = lane >> 4;
    f32x4 acc[4][4];
#pragma unroll
    for (int i = 0; i < 4; ++i)
#pragma unroll
        for (int j = 0; j < 4; ++j) acc[i][j] = (f32x4){0.f, 0.f, 0.f, 0.f};
    for (int k0 = 0; k0 < H; k0 += 32) {
        {
            const float* src = X + (size_t)(m0 + r) * H + k0 + kq * 16;
            U16S hi, lo;
#pragma unroll
            for (int j4 = 0; j4 < 4; ++j4) {
                float4 v = *(const float4*)(src + j4 * 4);
                float vv[4] = {v.x, v.y, v.z, v.w};
#pragma unroll
                for (int j = 0; j < 4; ++j) {
                    unsigned short h = f2bf(vv[j]);
                    hi.s[j4 * 4 + j] = h;
                    lo.s[j4 * 4 + j] = f2bf(vv[j] - bf2f(h));
                }
            }
            *(uint4*)&Ah[r][kq * 16] = hi.q[0];
            *(uint4*)&Ah[r][kq * 16 + 8] = hi.q[1];
            *(uint4*)&Al[r][kq * 16] = lo.q[0];
            *(uint4*)&Al[r][kq * 16 + 8] = lo.q[1];
        }
        {
            const float* src = W + (size_t)r * H + k0 + kq * 16;
            U16S hi, lo;
#pragma unroll
            for (int j4 = 0; j4 < 4; ++j4) {
                float4 v = *(const float4*)(src + j4 * 4);
                float vv[4] = {v.x, v.y, v.z, v.w};
#pragma unroll
                for (int j = 0; j < 4; ++j) {
                    unsigned short h = f2bf(vv[j]);
                    hi.s[j4 * 4 + j] = h;
                    lo.s[j4 * 4 + j] = f2bf(vv[j] - bf2f(h));
                }
            }
            *(uint4*)&Bh[r][kq * 16] = hi.q[0];
            *(uint4*)&Bh[r][kq * 16 + 8] = hi.q[1];
            *(uint4*)&Bl[r][kq * 16] = lo.q[0];
            *(uint4*)&Bl[r][kq * 16 + 8] = lo.q[1];
        }
        __syncthreads();
        bf16x8 ah[4], al[4], bh[4], bl[4];
#pragma unroll
        for (int mt = 0; mt < 4; ++mt) {
            ah[mt] = *(const bf16x8*)&Ah[wm + mt * 16 + lr][lq * 8];
            al[mt] = *(const bf16x8*)&Al[wm + mt * 16 + lr][lq * 8];
        }
#pragma unroll
        for (int nt = 0; nt < 4; ++nt) {
            bh[nt] = *(const bf16x8*)&Bh[wn + nt * 16 + lr][lq * 8];
            bl[nt] = *(const bf16x8*)&Bl[wn + nt * 16 + lr][lq * 8];
        }
#pragma unroll
        for (int mt = 0; mt < 4; ++mt)
#pragma unroll
            for (int nt = 0; nt < 4; ++nt) {
                acc[mt][nt] = MFMA16(ah[mt], bh[nt], acc[mt][nt]);
                acc[mt][nt] = MFMA16(ah[mt], bl[nt], acc[mt][nt]);
                acc[mt][nt] = MFMA16(al[mt], bh[nt], acc[mt][nt]);
            }
        __syncthreads();
    }
#pragma unroll
    for (int mt = 0; mt < 4; ++mt)
#pragma unroll
        for (int nt = 0; nt < 4; ++nt)
#pragma unroll
            for (int p = 0; p < 4; ++p) {
                int m = m0 + wm + mt * 16 + lq * 4 + p;
                int col = n0 + wn + nt * 16 + lr;
                O[(size_t)m * H + col] = res[(size_t)m * H + col] + acc[mt][nt][p];
            }
}

// ---------------- rope ----------------
__global__ void rope_kernel(float* __restrict__ q, float* __restrict__ k,
                            const int* __restrict__ pos) {
    int i = blockIdx.x * 256 + threadIdx.x;
    const int totq = T * NH * 64;
    const int tot = totq + T * NKV * 64;
    if (i >= tot) return;
    float* buf;
    int t, hh, d, nh;
    if (i < totq) {
        buf = q; nh = NH;
        int r = i; d = r & 63; r >>= 6; hh = r % NH; t = r / NH;
    } else {
        buf = k; nh = NKV;
        int r = i - totq; d = r & 63; r >>= 6; hh = r % NKV; t = r / NKV;
    }
    float p = (float)pos[t];
    float inv = powf(10000.0f, -(float)d / 64.0f);
    float fr = p * inv;
    float sv, cv;
    sincosf(fr, &sv, &cv);
    size_t bi = ((size_t)t * nh + hh) * HD + d;
    float x1 = buf[bi], x2 = buf[bi + 64];
    buf[bi] = x1 * cv - x2 * sv;
    buf[bi + 64] = x2 * cv + x1 * sv;
}

// ---------------- flash attention, compensated bf16 MFMA ----------------
#define KS_LD 140
#define VS_LD 42
#define PS_LD 34
__global__ __launch_bounds__(256) void attn_mfma(const float* __restrict__ Q,
                                                 const float* __restrict__ Kb,
                                                 const float* __restrict__ Vb,
                                                 float* __restrict__ O) {
    int h = blockIdx.x;
    int qb = blockIdx.y;
    int kvh = h >> 1;  // NH/NKV = 2
    int q0 = qb * 64;
    __shared__ short Ksh[32][KS_LD], Ksl[32][KS_LD];
    __shared__ short Vsh[128][VS_LD], Vsl[128][VS_LD];
    __shared__ short Ph[4][16][PS_LD], Pl[4][16][PS_LD];
    int tid = threadIdx.x;
    int wave = tid >> 6, lane = tid & 63;
    int lr = lane & 15, lq = lane >> 4;
    const float scale = 0.08838834764831845f;  // 1/sqrt(128)

    bf16x8 qh[4], ql[4];
    {
        const float* qrow = Q + (size_t)(q0 + wave * 16 + lr) * H + h * HD;
#pragma unroll
        for (int c = 0; c < 4; ++c) {
            float4 v0 = *(const float4*)(qrow + c * 32 + lq * 8);
            float4 v1 = *(const float4*)(qrow + c * 32 + lq * 8 + 4);
            float vv[8] = {v0.x, v0.y, v0.z, v0.w, v1.x, v1.y, v1.z, v1.w};
#pragma unroll
            for (int j = 0; j < 8; ++j) {
                unsigned short hb = f2bf(vv[j]);
                qh[c][j] = (short)hb;
                ql[c][j] = (short)f2bf(vv[j] - bf2f(hb));
            }
        }
    }
    f32x4 o[8];
#pragma unroll
    for (int nt = 0; nt < 8; ++nt) o[nt] = (f32x4){0.f, 0.f, 0.f, 0.f};
    float m_r[4] = {-1e30f, -1e30f, -1e30f, -1e30f};
    float l_r[4] = {0.f, 0.f, 0.f, 0.f};

    int ktmax = (q0 >> 5) + 2;
    int ntw = ((q0 + wave * 16 + 15) >> 5) + 1;
    int d0 = (tid & 31) * 4, rb = tid >> 5;

    for (int kt = 0; kt < ktmax; ++kt) {
        int k0 = kt * 32;
#pragma unroll
        for (int pass = 0; pass < 4; ++pass) {
            int key = rb + pass * 8;
            float4 v = *(const float4*)&Kb[(size_t)(k0 + key) * (NKV * HD) + kvh * HD + d0];
            float vv[4] = {v.x, v.y, v.z, v.w};
            uint2 hi, lo;
            unsigned short h0 = f2bf(vv[0]), h1 = f2bf(vv[1]);
            unsigned short h2b = f2bf(vv[2]), h3 = f2bf(vv[3]);
            hi.x = (unsigned)h0 | ((unsigned)h1 << 16);
            hi.y = (unsigned)h2b | ((unsigned)h3 << 16);
            lo.x = (unsigned)f2bf(vv[0] - bf2f(h0)) | ((unsigned)f2bf(vv[1] - bf2f(h1)) << 16);
            lo.y = (unsigned)f2bf(vv[2] - bf2f(h2b)) | ((unsigned)f2bf(vv[3] - bf2f(h3)) << 16);
            *(uint2*)&Ksh[key][d0] = hi;
            *(uint2*)&Ksl[key][d0] = lo;
        }
#pragma unroll
        for (int pass = 0; pass < 4; ++pass) {
            int key = rb + pass * 8;
            float4 v = *(const float4*)&Vb[(size_t)(k0 + key) * (NKV * HD) + kvh * HD + d0];
            float vv[4] = {v.x, v.y, v.z, v.w};
#pragma unroll
            for (int j = 0; j < 4; ++j) {
                unsigned short hb = f2bf(vv[j]);
                Vsh[d0 + j][key] = (short)hb;
                Vsl[d0 + j][key] = (short)f2bf(vv[j] - bf2f(hb));
            }
        }
        __syncthreads();
        if (kt < ntw) {
            f32x4 s[2];
            s[0] = (f32x4){0.f, 0.f, 0.f, 0.f};
            s[1] = (f32x4){0.f, 0.f, 0.f, 0.f};
#pragma unroll
            for (int nt = 0; nt < 2; ++nt)
#pragma unroll
                for (int c = 0; c < 4; ++c) {
                    bf16x8 kh = *(const bf16x8*)&Ksh[nt * 16 + lr][c * 32 + lq * 8];
                    bf16x8 kl = *(const bf16x8*)&Ksl[nt * 16 + lr][c * 32 + lq * 8];
                    s[nt] = MFMA16(qh[c], kh, s[nt]);
                    s[nt] = MFMA16(ql[c], kh, s[nt]);
                    s[nt] = MFMA16(qh[c], kl, s[nt]);
                }
            int gr_base = q0 + wave * 16 + lq * 4;
#pragma unroll
            for (int nt = 0; nt < 2; ++nt) {
                int gc = k0 + nt * 16 + lr;
#pragma unroll
                for (int p = 0; p < 4; ++p) {
                    float sv = s[nt][p] * scale;
                    if (gc > gr_base + p) sv = -1e30f;
                    s[nt][p] = sv;
                }
            }
            float alpha[4];
#pragma unroll
            for (int p = 0; p < 4; ++p) {
                float mx = fmaxf(s[0][p], s[1][p]);
#pragma unroll
                for (int off = 1; off < 16; off <<= 1) mx = fmaxf(mx, __shfl_xor(mx, off));
                float mn = fmaxf(m_r[p], mx);
                alpha[p] = __expf(m_r[p] - mn);
                float p0 = __expf(s[0][p] - mn);
                float p1 = __expf(s[1][p] - mn);
                float ps = p0 + p1;
#pragma unroll
                for (int off = 1; off < 16; off <<= 1) ps += __shfl_xor(ps, off);
                l_r[p] = l_r[p] * alpha[p] + ps;
                m_r[p] = mn;
                int r = lq * 4 + p;
                unsigned short h0 = f2bf(p0);
                Ph[wave][r][lr] = (short)h0;
                Pl[wave][r][lr] = (short)f2bf(p0 - bf2f(h0));
                unsigned short h1 = f2bf(p1);
                Ph[wave][r][lr + 16] = (short)h1;
                Pl[wave][r][lr + 16] = (short)f2bf(p1 - bf2f(h1));
            }
            bf16x8 pah = *(const bf16x8*)&Ph[wave][lr][lq * 8];
            bf16x8 pal = *(const bf16x8*)&Pl[wave][lr][lq * 8];
#pragma unroll
            for (int nt = 0; nt < 8; ++nt) {
#pragma unroll
                for (int p = 0; p < 4; ++p) o[nt][p] *= alpha[p];
                bf16x8 vh = *(const bf16x8*)&Vsh[nt * 16 + lr][lq * 8];
                bf16x8 vl = *(const bf16x8*)&Vsl[nt * 16 + lr][lq * 8];
                o[nt] = MFMA16(pah, vh, o[nt]);
                o[nt] = MFMA16(pal, vh, o[nt]);
                o[nt] = MFMA16(pah, vl, o[nt]);
            }
        }
        __syncthreads();
    }
    float linv[4];
#pragma unroll
    for (int p = 0; p < 4; ++p) linv[p] = 1.f / l_r[p];
#pragma unroll
    for (int nt = 0; nt < 8; ++nt)
#pragma unroll
        for (int p = 0; p < 4; ++p) {
            int row = q0 + wave * 16 + lq * 4 + p;
            O[(size_t)row * H + h * HD + nt * 16 + lr] = o[nt][p] * linv[p];
        }
}

// ---------------- router ----------------
__global__ void router_kernel(const float* __restrict__ logits, const float* __restrict__ bias,
                              int* __restrict__ topk_idx, float* __restrict__ topkw) {
    int t = blockIdx.x * 256 + threadIdx.x;
    if (t >= T) return;
    float sc[NE], sfc[NE];
    for (int e = 0; e < NE; ++e) {
        float s = 1.f / (1.f + expf(-logits[(size_t)t * NE + e]));
        sc[e] = s;
        sfc[e] = s + bias[e];
    }
    float gs[NG];
    for (int g = 0; g < NG; ++g) {
        float m1 = -1e30f, m2 = -1e30f;
        for (int i = 0; i < 4; ++i) {
            float v = sfc[g * 4 + i];
            if (v > m1) { m2 = m1; m1 = v; }
            else if (v > m2) m2 = v;
        }
        gs[g] = m1 + m2;
    }
    bool gmask[NG];
    for (int g = 0; g < NG; ++g) gmask[g] = false;
    for (int r = 0; r < 4; ++r) {
        int bi = 0; float bv = -1e30f;
        for (int g = 0; g < NG; ++g)
            if (gs[g] > bv) { bv = gs[g]; bi = g; }
        gmask[bi] = true;
        gs[bi] = -1e30f;
    }
    float msfc[NE];
    for (int e = 0; e < NE; ++e) msfc[e] = gmask[e >> 2] ? sfc[e] : 0.f;
    int idx[TOPK]; float w[TOPK]; float wsum = 0.f;
    for (int r = 0; r < TOPK; ++r) {
        int bi = 0; float bv = -1e30f;
        for (int e = 0; e < NE; ++e)
            if (msfc[e] > bv) { bv = msfc[e]; bi = e; }
        idx[r] = bi;
        msfc[bi] = -1e30f;
        w[r] = sc[bi];
        wsum += w[r];
    }
    float inv = RSF / (wsum + 1e-20f);
    for (int r = 0; r < TOPK; ++r) {
        topk_idx[(size_t)t * TOPK + r] = idx[r];
        topkw[(size_t)t * TOPK + r] = w[r] * inv;
    }
}

__global__ void count_kernel(const int* __restrict__ topk_idx, int* __restrict__ counts) {
    int i = blockIdx.x * 256 + threadIdx.x;
    if (i < T * TOPK) atomicAdd(&counts[topk_idx[i]], 1);
}
__global__ void scan_kernel(const int* __restrict__ counts, int* __restrict__ offs) {
    if (threadIdx.x == 0 && blockIdx.x == 0) {
        int acc = 0;
        for (int e = 0; e < NE; ++e) { offs[e] = acc; acc += counts[e]; }
    }
}
__global__ void fill_kernel(const int* __restrict__ topk_idx,
                            const int* __restrict__ offs, int* __restrict__ fills,
                            int* __restrict__ tok_of, int* __restrict__ slot_of) {
    int i = blockIdx.x * 256 + threadIdx.x;
    if (i < T * TOPK) {
        int e = topk_idx[i];
        int p = offs[e] + atomicAdd(&fills[e], 1);
        tok_of[p] = i >> 2;
        slot_of[i] = p;
    }
}

// ---------------- dual up-proj: bf16 A (gathered) x bf16 BT weights, async staging ----
// 128m x (64 gate + 64 up) tile, BK=64 as 2x32 chunks, global_load_lds for A,G,U.
__global__ __launch_bounds__(256) void up_mfma2(
    const unsigned short* __restrict__ Xb, const unsigned short* __restrict__ Gt,
    const unsigned short* __restrict__ Ut, size_t wstride, const int* __restrict__ tok_of,
    const int* __restrict__ offs, const int* __restrict__ counts, int eoff,
    unsigned short* __restrict__ outb, int ldo) {
    int zl = blockIdx.z;
    int e = eoff + zl;
    int cnt = counts ? counts[e] : T;
    int base = offs ? offs[e] : 0;
    int m0 = blockIdx.y * 128;
    if (m0 >= cnt) return;
    int n0 = blockIdx.x * 64;
    const unsigned short* gt = Gt + (size_t)zl * wstride;
    const unsigned short* ut = Ut + (size_t)zl * wstride;
    __shared__ short As[2][128][32];
    __shared__ short Gs[2][64][32];
    __shared__ short Us[2][64][32];
    __shared__ int toks[128];
    int tid = threadIdx.x;
    if (tid < 128) {
        int m = m0 + tid;
        if (m >= cnt) m = cnt - 1;
        toks[tid] = tok_of ? tok_of[base + m] : m;
    }
    __syncthreads();
    int wave = tid >> 6, lane = tid & 63;
    int lr = lane & 15, lq = lane >> 4;
    int wm = (wave >> 1) * 64, wn = (wave & 1) * 32;
    int srow = lane >> 2, skb = (lane & 3) * 8;  // 4 lanes per 32-bf16 row
    const unsigned short* aptr[2];
#pragma unroll
    for (int p = 0; p < 2; ++p)
        aptr[p] = Xb + (size_t)toks[wave * 32 + p * 16 + srow] * H + skb;
    const unsigned short* gptr = gt + (size_t)(n0 + wave * 16 + srow) * H + skb;
    const unsigned short* uptr = ut + (size_t)(n0 + wave * 16 + srow) * H + skb;
    f32x4 ag[4][2], au[4][2];
#pragma unroll
    for (int i = 0; i < 4; ++i)
#pragma unroll
        for (int j = 0; j < 2; ++j) {
            ag[i][j] = (f32x4){0.f, 0.f, 0.f, 0.f};
            au[i][j] = (f32x4){0.f, 0.f, 0.f, 0.f};
        }
    for (int k0 = 0; k0 < H; k0 += 64) {
#pragma unroll
        for (int c = 0; c < 2; ++c) {
            int kc = k0 + c * 32;
#pragma unroll
            for (int p = 0; p < 2; ++p)
                gl16(aptr[p] + kc, &As[c][wave * 32 + p * 16 + srow][skb]);
            gl16(gptr + kc, &Gs[c][wave * 16 + srow][skb]);
            gl16(uptr + kc, &Us[c][wave * 16 + srow][skb]);
        }
        __syncthreads();
#pragma unroll
        for (int c = 0; c < 2; ++c) {
            bf16x8 a[4], gg[2], uu[2];
#pragma unroll
            for (int mt = 0; mt < 4; ++mt)
                a[mt] = *(const bf16x8*)&As[c][wm + mt * 16 + lr][lq * 8];
#pragma unroll
            for (int nt = 0; nt < 2; ++nt) {
                gg[nt] = *(const bf16x8*)&Gs[c][wn + nt * 16 + lr][lq * 8];
                uu[nt] = *(const bf16x8*)&Us[c][wn + nt * 16 + lr][lq * 8];
            }
#pragma unroll
            for (int mt = 0; mt < 4; ++mt)
#pragma unroll
                for (int nt = 0; nt < 2; ++nt) {
                    ag[mt][nt] = MFMA16(a[mt], gg[nt], ag[mt][nt]);
                    au[mt][nt] = MFMA16(a[mt], uu[nt], au[mt][nt]);
                }
        }
        __syncthreads();
    }
#pragma unroll
    for (int mt = 0; mt < 4; ++mt)
#pragma unroll
        for (int nt = 0; nt < 2; ++nt)
#pragma unroll
            for (int p = 0; p < 4; ++p) {
                int m = m0 + wm + mt * 16 + lq * 4 + p;
                if (m >= cnt) continue;
                int orow = tok_of ? base + m : m;
                int col = n0 + wn + nt * 16 + lr;
                float gv = ag[mt][nt][p], uv = au[mt][nt][p];
                float sv = gv / (1.f + __expf(-gv)) * uv;
                outb[(size_t)orow * ldo + col] = f2bf(sv);
            }
}

// ---------------- down-proj: bf16 A x bf16 BT weights, async staging, fp32 out -------
// 128m x 128n tile, BK=64 as 2x32 chunks. A rows = slots (or tokens), row length K.
__global__ __launch_bounds__(256) void down_mfma2(const unsigned short* __restrict__ Ab, int K,
                                                  const unsigned short* __restrict__ Wt,
                                                  size_t wstride, const int* __restrict__ offs,
                                                  const int* __restrict__ counts, int eoff,
                                                  float* __restrict__ Co) {
    int zl = blockIdx.z;
    int e = eoff + zl;
    int cnt = counts ? counts[e] : T;
    int base = offs ? offs[e] : 0;
    int m0 = blockIdx.y * 128;
    if (m0 >= cnt) return;
    int n0 = blockIdx.x * 128;
    const unsigned short* wt = Wt + (size_t)zl * wstride;
    __shared__ short As[2][128][32];
    __shared__ short Bs[2][128][32];
    int tid = threadIdx.x;
    int wave = tid >> 6, lane = tid & 63;
    int lr = lane & 15, lq = lane >> 4;
    int wm = (wave >> 1) * 64, wn = (wave & 1) * 64;
    int srow = lane >> 2, skb = (lane & 3) * 8;
    const unsigned short* aptr[2];
    const unsigned short* bptr[2];
#pragma unroll
    for (int p = 0; p < 2; ++p) {
        int m = m0 + wave * 32 + p * 16 + srow;
        if (m >= cnt) m = cnt - 1;
        aptr[p] = Ab + (size_t)(base + m) * K + skb;
        bptr[p] = wt + (size_t)(n0 + wave * 32 + p * 16 + srow) * K + skb;
    }
    f32x4 acc[4][4];
#pragma unroll
    for (int i = 0; i < 4; ++i)
#pragma unroll
        for (int j = 0; j < 4; ++j) acc[i][j] = (f32x4){0.f, 0.f, 0.f, 0.f};
    for (int k0 = 0; k0 < K; k0 += 64) {
#pragma unroll
        for (int c = 0; c < 2; ++c) {
            int kc = k0 + c * 32;
#pragma unroll
            for (int p = 0; p < 2; ++p) {
                gl16(aptr[p] + kc, &As[c][wave * 32 + p * 16 + srow][skb]);
                gl16(bptr[p] + kc, &Bs[c][wave * 32 + p * 16 + srow][skb]);
            }
        }
        __syncthreads();
#pragma unroll
        for (int c = 0; c < 2; ++c) {
            bf16x8 a[4], b[4];
#pragma unroll
            for (int mt = 0; mt < 4; ++mt)
                a[mt] = *(const bf16x8*)&As[c][wm + mt * 16 + lr][lq * 8];
#pragma unroll
            for (int nt = 0; nt < 4; ++nt)
                b[nt] = *(const bf16x8*)&Bs[c][wn + nt * 16 + lr][lq * 8];
#pragma unroll
            for (int mt = 0; mt < 4; ++mt)
#pragma unroll
                for (int nt = 0; nt < 4; ++nt) acc[mt][nt] = MFMA16(a[mt], b[nt], acc[mt][nt]);
        }
        __syncthreads();
    }
#pragma unroll
    for (int mt = 0; mt < 4; ++mt)
#pragma unroll
        for (int nt = 0; nt < 4; ++nt)
#pragma unroll
            for (int p = 0; p < 4; ++p) {
                int m = m0 + wm + mt * 16 + lq * 4 + p;
                if (m >= cnt) continue;
                int col = n0 + wn + nt * 16 + lr;
                Co[(size_t)(base + m) * H + col] = acc[mt][nt][p];
            }
}

// ---------------- final combine ----------------
__global__ void combine_kernel(const float* __restrict__ o_slot, const int* __restrict__ slot_of,
                               const float* __restrict__ topkw, const float* __restrict__ h2,
                               const float* __restrict__ sharedo, float* __restrict__ out) {
    int t = blockIdx.x;
    int d = threadIdx.x * 4;
    float4 a = *(const float4*)&h2[(size_t)t * H + d];
    float4 b = *(const float4*)&sharedo[(size_t)t * H + d];
    float4 acc = make_float4(a.x + b.x, a.y + b.y, a.z + b.z, a.w + b.w);
#pragma unroll
    for (int r = 0; r < TOPK; ++r) {
        int s = slot_of[t * TOPK + r];
        float w = topkw[t * TOPK + r];
        float4 v = *(const float4*)&o_slot[(size_t)s * H + d];
        acc.x += w * v.x; acc.y += w * v.y; acc.z += w * v.z; acc.w += w * v.w;
    }
    *(float4*)&out[(size_t)t * H + d] = acc;
}

// ---------------- launch ----------------
extern "C" void kernel_launch(void* const* d_in, const int* in_sizes, int n_in,
                              void* d_out, int out_size, void* d_ws, size_t ws_size,
                              hipStream_t stream) {
    const float* hidden = (const float*)d_in[0];
    const int* pos = (const int*)d_in[1];
    const float* ln1w = (const float*)d_in[2];
    const float* ln2w = (const float*)d_in[3];
    const float* q_w = (const float*)d_in[4];
    const float* k_w = (const float*)d_in[5];
    const float* v_w = (const float*)d_in[6];
    const float* o_w = (const float*)d_in[7];
    const float* router_w = (const float*)d_in[8];
    const float* router_b = (const float*)d_in[9];
    const float* eg_w = (const float*)d_in[10];
    const float* eu_w = (const float*)d_in[11];
    const float* ed_w = (const float*)d_in[12];
    const float* sg_w = (const float*)d_in[13];
    const float* su_w = (const float*)d_in[14];
    const float* sd_w = (const float*)d_in[15];
    float* out = (float*)d_out;

    float* f = (float*)d_ws;
    // --- arena region (32 MB): attention-phase buffers, reused for bf16 weights later
    float* h_ln1 = f;   f += (size_t)T * H;          // 4 MB
    float* qb = f;      f += (size_t)T * H;          // 4 MB
    float* kb = f;      f += (size_t)T * NKV * HD;   // 2 MB
    float* vb = f;      f += (size_t)T * NKV * HD;   // 2 MB
    float* attno = f;   f += (size_t)T * H;          // 4 MB
    f += (size_t)4 * 1024 * 1024;                    // 16 MB arena extension
    // --- persistent buffers
    float* h2 = f;      f += (size_t)T * H;
    float* h_ln2f = f;  f += (size_t)T * H;
    float* logits = f;  f += (size_t)T * NE;
    float* topkw = f;   f += (size_t)T * TOPK;
    float* o_slot = f;  f += (size_t)T * TOPK * H;
    float* sharedo = f; f += (size_t)T * H;
    unsigned short* h_ln2b = (unsigned short*)f;
    unsigned short* abuf = h_ln2b + (size_t)T * H;
    unsigned short* ashared = abuf + (size_t)T * TOPK * MI;
    int* topk_idx = (int*)(ashared + (size_t)T * SI);
    int* counts = topk_idx + T * TOPK;
    int* fills = counts + NE;
    int* offs = fills + NE;
    int* tok_of = offs + NE;
    int* slot_of = tok_of + T * TOPK;

    // arena views (16 experts per group): egT/euT = 8M shorts each; edT = 8M; sgT/suT/sdT small
    unsigned short* arena = (unsigned short*)h_ln1;
    unsigned short* egT = arena;
    unsigned short* euT = arena + (size_t)16 * H * MI;
    unsigned short* edT = arena;
    unsigned short* sgT = arena;
    unsigned short* suT = arena + (size_t)H * SI;
    unsigned short* sdT = arena;

    dim3 b256(256);

    rmsnorm_kernel<<<T, b256, 0, stream>>>(hidden, ln1w, h_ln1);
    gemm_qkv_mfma<<<dim3(16, 8), b256, 0, stream>>>(h_ln1, q_w, k_w, v_w, qb, kb, vb);
    {
        int tot = T * NH * 64 + T * NKV * 64;
        rope_kernel<<<(tot + 255) / 256, b256, 0, stream>>>(qb, kb, pos);
    }
    attn_mfma<<<dim3(NH, T / 64), b256, 0, stream>>>(qb, kb, vb, attno);
    gemm_bt_res_mfma<<<dim3(8, 8), b256, 0, stream>>>(attno, o_w, hidden, h2);
    rmsnorm_dual_kernel<<<T, b256, 0, stream>>>(h2, ln2w, h_ln2f, h_ln2b);

    gemm_small_bt<<<dim3(1, T / GT), b256, 0, stream>>>(h_ln2f, router_w, logits, T, NE, H);
    router_kernel<<<(T + 255) / 256, b256, 0, stream>>>(logits, router_b, topk_idx, topkw);
    zero_i_kernel<<<1, b256, 0, stream>>>(counts, 2 * NE);
    count_kernel<<<(T * TOPK + 255) / 256, b256, 0, stream>>>(topk_idx, counts);
    scan_kernel<<<1, 1, 0, stream>>>(counts, offs);
    fill_kernel<<<(T * TOPK + 255) / 256, b256, 0, stream>>>(topk_idx, offs, fills, tok_of, slot_of);

    // ---- MoE up: 2 expert groups of 16 through the 32 MB arena ----
    for (int g = 0; g < 2; ++g) {
        int eo = g * 16;
        transpose_cvt<<<dim3(MI / 64, H / 64, 16), b256, 0, stream>>>(eg_w, egT, H, MI, eo);
        transpose_cvt<<<dim3(MI / 64, H / 64, 16), b256, 0, stream>>>(eu_w, euT, H, MI, eo);
        up_mfma2<<<dim3(MI / 64, 8, 16), b256, 0, stream>>>(
            h_ln2b, egT, euT, (size_t)H * MI, tok_of, offs, counts, eo, abuf, MI);
    }
    // ---- MoE down ----
    for (int g = 0; g < 2; ++g) {
        int eo = g * 16;
        transpose_cvt<<<dim3(H / 64, MI / 64, 16), b256, 0, stream>>>(ed_w, edT, MI, H, eo);
        down_mfma2<<<dim3(H / 128, 8, 16), b256, 0, stream>>>(
            abuf, MI, edT, (size_t)MI * H, offs, counts, eo, o_slot);
    }
    // ---- shared expert ----
    transpose_cvt<<<dim3(SI / 64, H / 64, 1), b256, 0, stream>>>(sg_w, sgT, H, SI, 0);
    transpose_cvt<<<dim3(SI / 64, H / 64, 1), b256, 0, stream>>>(su_w, suT, H, SI, 0);
    up_mfma2<<<dim3(SI / 64, T / 128, 1), b256, 0, stream>>>(
        h_ln2b, sgT, suT, 0, nullptr, nullptr, nullptr, 0, ashared, SI);
    transpose_cvt<<<dim3(H / 64, SI / 64, 1), b256, 0, stream>>>(sd_w, sdT, SI, H, 0);
    down_mfma2<<<dim3(H / 128, T / 128, 1), b256, 0, stream>>>(
        ashared, SI, sdT, 0, nullptr, nullptr, 0, sharedo);

    combine_kernel<<<T, b256, 0, stream>>>(o_slot, slot_of, topkw, h2, sharedo, out);
}